// Round 1
// baseline (17100.517 us; speedup 1.0000x reference)
//
#include <hip/hip_runtime.h>
#include <math.h>

// 0 = partitionable threefry (modern JAX >= 0.4.36 default), 1 = original counter-split
#define EPS_MODE 0

static constexpr int T   = 16;
static constexpr int B   = 64;
static constexpr int NND = 1024;
static constexpr int C1  = 64;
static constexpr int C2  = 128;
static constexpr int R   = NND * B;        // 65536 gate-gemm rows
static constexpr int DK  = 196608;
static constexpr int KCH = 96;             // dense split-K chunks
static constexpr int KCHUNK = DK / KCH;    // 2048
static constexpr size_t M1F = 1048576;     // 1M floats

// ---------------- transpose xs [1024(t,b)][1024 j] -> xTT [j][(t,b)] ----------------
__global__ __launch_bounds__(256) void transpose1024(const float* __restrict__ in,
                                                     float* __restrict__ out) {
  __shared__ float tile[32][33];
  int bx = blockIdx.x * 32, by = blockIdx.y * 32;
  int tx = threadIdx.x, ty = threadIdx.y;  // (32,8)
  for (int k = 0; k < 32; k += 8)
    tile[ty + k][tx] = in[(size_t)(by + ty + k) * 1024 + bx + tx];
  __syncthreads();
  for (int k = 0; k < 32; k += 8)
    out[(size_t)(bx + ty + k) * 1024 + by + tx] = tile[tx][ty + k];
}

// ---------------- big GEMM: OUT[1024][ncols] = adj[1024][1024] @ X[1024][ncols] -----
// SCATTER=1: OUT index = (c>>6)*65536 + r*64 + (c&63)   (used for per-t AX layout)
template <int SCATTER>
__global__ __launch_bounds__(256) void sgemm_adj(const float* __restrict__ A,
                                                 const float* __restrict__ Bm,
                                                 float* __restrict__ C, int ncols) {
  __shared__ float As[8][128];
  __shared__ float Bs[8][128];
  int tid = threadIdx.x;
  int bm = blockIdx.y, bn = blockIdx.x;
  int row0 = bm * 128, col0 = bn * 128;
  float acc[8][8] = {};
  int tx = tid & 15, ty = tid >> 4;
  int arow = tid >> 1;         // 0..127
  int acol = (tid & 1) * 4;    // 0 / 4
  int brow = tid >> 5;         // 0..7
  int bcol = (tid & 31) * 4;   // 0..124
  const float* Aptr = A + (size_t)(row0 + arow) * 1024 + acol;
  const float* Bptr = Bm + (size_t)brow * ncols + col0 + bcol;
  for (int k0 = 0; k0 < 1024; k0 += 8) {
    float4 av = *reinterpret_cast<const float4*>(Aptr + k0);
    float4 bv = *reinterpret_cast<const float4*>(Bptr + (size_t)k0 * ncols);
    As[acol + 0][arow] = av.x; As[acol + 1][arow] = av.y;
    As[acol + 2][arow] = av.z; As[acol + 3][arow] = av.w;
    *reinterpret_cast<float4*>(&Bs[brow][bcol]) = bv;
    __syncthreads();
#pragma unroll
    for (int kk = 0; kk < 8; ++kk) {
      float a[8], b[8];
      *reinterpret_cast<float4*>(a)     = *reinterpret_cast<const float4*>(&As[kk][ty * 4]);
      *reinterpret_cast<float4*>(a + 4) = *reinterpret_cast<const float4*>(&As[kk][ty * 4 + 64]);
      *reinterpret_cast<float4*>(b)     = *reinterpret_cast<const float4*>(&Bs[kk][tx * 4]);
      *reinterpret_cast<float4*>(b + 4) = *reinterpret_cast<const float4*>(&Bs[kk][tx * 4 + 64]);
#pragma unroll
      for (int i = 0; i < 8; ++i)
#pragma unroll
        for (int j = 0; j < 8; ++j) acc[i][j] += a[i] * b[j];
    }
    __syncthreads();
  }
#pragma unroll
  for (int i = 0; i < 8; ++i) {
    int r = row0 + ty * 4 + (i & 3) + (i >> 2) * 64;
#pragma unroll
    for (int j = 0; j < 8; ++j) {
      int c = col0 + tx * 4 + (j & 3) + (j >> 2) * 64;
      if (SCATTER)
        C[(size_t)(c >> 6) * 65536 + (size_t)r * 64 + (c & 63)] = acc[i][j];
      else
        C[(size_t)r * ncols + c] = acc[i][j];
    }
  }
}

// ---------------- gate GEMM over R=65536 rows ---------------------------------------
// A(row,k) = k<K1 ? A1[row*K1+k] : A2[row*K2+(k-K1)] ; W [K1+K2][C], bias [C]
// MODE 0: out = sigmoid(g + bias)
// MODE 1: H[row*C+c] = (1-z)*H + z*tanh(g + bias), z from Zp (GRU update, in-place)
template <int MODE>
__global__ __launch_bounds__(256) void gate_gemm(const float* __restrict__ A1, int K1,
                                                 const float* __restrict__ A2, int K2,
                                                 const float* __restrict__ W,
                                                 const float* __restrict__ bias, int C,
                                                 float* __restrict__ out,
                                                 const float* __restrict__ Zp,
                                                 float* __restrict__ H) {
  __shared__ float As[128][17];
  __shared__ float Ws[16][64];
  int tid = threadIdx.x;
  int row0 = blockIdx.y * 128, col0 = blockIdx.x * 64;
  int K = K1 + K2;
  float acc[8][4] = {};
  int tx = tid & 15, ty = tid >> 4;
  for (int k0 = 0; k0 < K; k0 += 16) {
    int k = k0 + (tid & 15);
#pragma unroll
    for (int i = 0; i < 8; ++i) {
      int row = row0 + (tid >> 4) + i * 16;
      float v = 0.f;
      if (k < K1) v = A1[(size_t)row * K1 + k];
      else if (k < K) v = A2[(size_t)row * K2 + (k - K1)];
      As[(tid >> 4) + i * 16][tid & 15] = v;
    }
#pragma unroll
    for (int i = 0; i < 4; ++i) {
      int kk = (tid >> 6) + i * 4;
      int kg = k0 + kk;
      Ws[kk][tid & 63] = (kg < K) ? W[(size_t)kg * C + col0 + (tid & 63)] : 0.f;
    }
    __syncthreads();
#pragma unroll
    for (int kk = 0; kk < 16; ++kk) {
      float b[4];
      *reinterpret_cast<float4*>(b) = *reinterpret_cast<const float4*>(&Ws[kk][tx * 4]);
#pragma unroll
      for (int i = 0; i < 8; ++i) {
        float a = As[ty + i * 16][kk];
        acc[i][0] += a * b[0]; acc[i][1] += a * b[1];
        acc[i][2] += a * b[2]; acc[i][3] += a * b[3];
      }
    }
    __syncthreads();
  }
#pragma unroll
  for (int i = 0; i < 8; ++i) {
    int row = row0 + ty + i * 16;
#pragma unroll
    for (int j = 0; j < 4; ++j) {
      int c = col0 + tx * 4 + j;
      float g = acc[i][j] + bias[c];
      size_t idx = (size_t)row * C + c;
      if (MODE == 0) {
        out[idx] = 1.f / (1.f + expf(-g));
      } else {
        float z = Zp[idx], h = H[idx];
        H[idx] = (1.f - z) * h + z * tanhf(g);
      }
    }
  }
}

// ---------------- elementwise a *= b ------------------------------------------------
__global__ __launch_bounds__(256) void mul_inplace(float* __restrict__ a,
                                                   const float* __restrict__ b, int n) {
  int n4 = n >> 2;
  for (int i = blockIdx.x * blockDim.x + threadIdx.x; i < n4;
       i += gridDim.x * blockDim.x) {
    float4 x = reinterpret_cast<float4*>(a)[i];
    float4 y = reinterpret_cast<const float4*>(b)[i];
    x.x *= y.x; x.y *= y.y; x.z *= y.z; x.w *= y.w;
    reinterpret_cast<float4*>(a)[i] = x;
  }
}

// ---------------- build XST[k=n*192+c][b] from h1[n][b][c1], h2[n][b][c2] -----------
__global__ __launch_bounds__(256) void build_xst(const float* __restrict__ h1,
                                                 const float* __restrict__ h2,
                                                 float* __restrict__ xst) {
  int n = blockIdx.x;
  __shared__ float t1[64][65];
  __shared__ float t2[128][65];
  int tid = threadIdx.x;
#pragma unroll
  for (int i = 0; i < 16; ++i) {
    int b = (tid >> 6) + i * 4;
    int c = tid & 63;
    t1[c][b] = h1[((size_t)n * 64 + b) * 64 + c];
  }
#pragma unroll
  for (int i = 0; i < 32; ++i) {
    int b = (tid >> 7) + i * 2;
    int c = tid & 127;
    t2[c][b] = h2[((size_t)n * 64 + b) * 128 + c];
  }
  __syncthreads();
#pragma unroll
  for (int i = 0; i < 48; ++i) {
    int c = (tid >> 6) + i * 4;
    int b = tid & 63;
    float v = (c < 64) ? t1[c][b] : t2[c - 64][b];
    xst[((size_t)n * 192 + c) * 64 + b] = v;
  }
}

// ---------------- dense split-K partials: P[mat][chunk][64 b][256 o] ----------------
__global__ __launch_bounds__(256) void dense_partial(const float* __restrict__ xst,
                                                     const float* __restrict__ Wmu,
                                                     const float* __restrict__ Wlv,
                                                     float* __restrict__ P) {
  int ot = blockIdx.x, ch = blockIdx.y, mat = blockIdx.z;
  const float* W = mat ? Wlv : Wmu;
  __shared__ float As[16][64];
  __shared__ float Ws[16][64];
  int tid = threadIdx.x;
  int tx = tid & 15, ty = tid >> 4;
  float acc[4][4] = {};
  int k0base = ch * KCHUNK;
  for (int k0 = 0; k0 < KCHUNK; k0 += 16) {
#pragma unroll
    for (int i = 0; i < 4; ++i) {
      int kk = (tid >> 6) + i * 4;
      int kg = k0base + k0 + kk;
      As[kk][tid & 63] = xst[(size_t)kg * 64 + (tid & 63)];
      Ws[kk][tid & 63] = W[(size_t)kg * 256 + ot * 64 + (tid & 63)];
    }
    __syncthreads();
#pragma unroll
    for (int kk = 0; kk < 16; ++kk) {
      float a[4], b[4];
      *reinterpret_cast<float4*>(a) = *reinterpret_cast<const float4*>(&As[kk][ty * 4]);
      *reinterpret_cast<float4*>(b) = *reinterpret_cast<const float4*>(&Ws[kk][tx * 4]);
#pragma unroll
      for (int i = 0; i < 4; ++i)
#pragma unroll
        for (int j = 0; j < 4; ++j) acc[i][j] += a[i] * b[j];
    }
    __syncthreads();
  }
#pragma unroll
  for (int i = 0; i < 4; ++i)
#pragma unroll
    for (int j = 0; j < 4; ++j) {
      int brow = ty * 4 + i, o = ot * 64 + tx * 4 + j;
      P[(((size_t)mat * KCH + ch) * 64 + brow) * 256 + o] = acc[i][j];
    }
}

// ---------------- threefry-2x32 (JAX-compatible) ------------------------------------
__device__ __forceinline__ unsigned rotl32(unsigned v, int s) {
  return (v << s) | (v >> (32 - s));
}
__device__ void threefry(unsigned k0, unsigned k1, unsigned x0, unsigned x1,
                         unsigned& o0, unsigned& o1) {
  unsigned ks2 = k0 ^ k1 ^ 0x1BD11BDAu;
  unsigned a = x0 + k0, b = x1 + k1;
#define TF_RND(rot) { a += b; b = rotl32(b, rot); b ^= a; }
  TF_RND(13) TF_RND(15) TF_RND(26) TF_RND(6)
  a += k1; b += ks2 + 1u;
  TF_RND(17) TF_RND(29) TF_RND(16) TF_RND(24)
  a += ks2; b += k0 + 2u;
  TF_RND(13) TF_RND(15) TF_RND(26) TF_RND(6)
  a += k0; b += k1 + 3u;
  TF_RND(17) TF_RND(29) TF_RND(16) TF_RND(24)
  a += k1; b += ks2 + 4u;
  TF_RND(13) TF_RND(15) TF_RND(26) TF_RND(6)
  a += ks2; b += k0 + 5u;
#undef TF_RND
  o0 = a; o1 = b;
}

__device__ float u32_to_normal(unsigned bits) {
  unsigned fb = (bits >> 9) | 0x3F800000u;
  float f = __uint_as_float(fb) - 1.0f;  // [0,1)
  const float lo = -0.99999994f;         // nextafter(-1,0) in f32
  float u = f * 2.0f + lo;               // (hi-lo) rounds to exactly 2.0f
  u = fmaxf(lo, u);
  float w = -log1pf(-u * u);
  float p;
  if (w < 5.0f) {
    w -= 2.5f;
    p = 2.81022636e-08f;
    p = fmaf(p, w, 3.43273939e-07f);
    p = fmaf(p, w, -3.5233877e-06f);
    p = fmaf(p, w, -4.39150654e-06f);
    p = fmaf(p, w, 0.00021858087f);
    p = fmaf(p, w, -0.00125372503f);
    p = fmaf(p, w, -0.00417768164f);
    p = fmaf(p, w, 0.246640727f);
    p = fmaf(p, w, 1.50140941f);
  } else {
    w = sqrtf(w) - 3.0f;
    p = -0.000200214257f;
    p = fmaf(p, w, 0.000100950558f);
    p = fmaf(p, w, 0.00134934322f);
    p = fmaf(p, w, -0.00367342844f);
    p = fmaf(p, w, 0.00573950773f);
    p = fmaf(p, w, -0.0076224613f);
    p = fmaf(p, w, 0.00943887047f);
    p = fmaf(p, w, 1.00167406f);
    p = fmaf(p, w, 2.83297682f);
  }
  return 1.41421354f * (p * u);  // sqrt(2) * erfinv(u)
}

__global__ __launch_bounds__(256) void eps_kernel(float* __restrict__ eps) {
  int b = blockIdx.x;    // 64
  int o = threadIdx.x;   // 256
  unsigned k0, k1;
  threefry(0u, 0u, 0u, 1234u, k0, k1);  // fold_in(key(0), 1234)
  float s = 0.f;
  for (int smp = 0; smp < 50; ++smp) {
    unsigned idx = ((unsigned)smp * 64u + (unsigned)b) * 256u + (unsigned)o;
    unsigned o0, o1, bits;
#if EPS_MODE == 0
    threefry(k0, k1, 0u, idx, o0, o1);
    bits = o0 ^ o1;
#else
    unsigned p = idx % 409600u, half = idx / 409600u;
    threefry(k0, k1, p, p + 409600u, o0, o1);
    bits = half ? o1 : o0;
#endif
    s += u32_to_normal(bits);
  }
  eps[b * 256 + o] = s / 50.0f;
}

// ---------------- final reduce + heads + reparam ------------------------------------
__global__ __launch_bounds__(256) void final_kernel(const float* __restrict__ P,
                                                    const float* __restrict__ bmu,
                                                    const float* __restrict__ blv,
                                                    const float* __restrict__ eps,
                                                    float* __restrict__ out) {
  int b = blockIdx.x, o = threadIdx.x;
  float smu = 0.f, slv = 0.f;
  for (int ch = 0; ch < KCH; ++ch) {
    smu += P[(((size_t)0 * KCH + ch) * 64 + b) * 256 + o];
    slv += P[(((size_t)1 * KCH + ch) * 64 + b) * 256 + o];
  }
  float mu = 1.f / (1.f + expf(-(smu + bmu[o])));
  float lv = 1.f / (1.f + expf(-(slv + blv[o])));
  float z = mu + eps[b * 256 + o] * expf(0.5f * lv);
  out[b * 256 + o] = z;
  out[16384 + b * 256 + o] = mu;
  out[32768 + b * 256 + o] = lv;
}

// ------------------------------------------------------------------------------------
extern "C" void kernel_launch(void* const* d_in, const int* in_sizes, int n_in,
                              void* d_out, int out_size, void* d_ws, size_t ws_size,
                              hipStream_t stream) {
  (void)in_sizes; (void)n_in; (void)out_size; (void)ws_size;
  const float* xs  = (const float*)d_in[0];
  const float* adj = (const float*)d_in[1];
  const float* Wg[2][3] = {
      {(const float*)d_in[2], (const float*)d_in[4], (const float*)d_in[6]},
      {(const float*)d_in[8], (const float*)d_in[10], (const float*)d_in[12]}};
  const float* bgv[2][3] = {
      {(const float*)d_in[3], (const float*)d_in[5], (const float*)d_in[7]},
      {(const float*)d_in[9], (const float*)d_in[11], (const float*)d_in[13]}};
  const float* Wmu = (const float*)d_in[14];
  const float* bmu = (const float*)d_in[15];
  const float* Wlv = (const float*)d_in[16];
  const float* blv = (const float*)d_in[17];

  float* ws  = (float*)d_ws;
  float* xTT = ws;               // [1024 j][1024 (t,b)]         1M
  float* AX  = ws + 1 * M1F;     // [T][1024 i][64 b]            1M
  float* h1  = ws + 2 * M1F;     // [1024][64][64]               4M
  float* h2  = ws + 6 * M1F;     // [1024][64][128]              8M
  float* AH1 = ws + 14 * M1F;    // adj@h1                       4M
  float* AH2 = ws + 18 * M1F;    // adj@h2                       8M
  float* ZB  = ws + 26 * M1F;    // z gate buffer                8M
  float* RB  = ws + 34 * M1F;    // r gate / r*h buffer          8M
  float* SCR = ws + 42 * M1F;    // adj@(r*h)                    8M
  float* XST = ws + 14 * M1F;    // [196608][64] alias (post-loop)   12.6M
  float* P   = ws + 28 * M1F;    // dense partials 2*96*64*256   3.2M (alias)
  float* EPS = ws + 32 * M1F;    // [64][256]

  // zero h1,h2,AH1,AH2 (contiguous 2M..26M floats)
  hipMemsetAsync(ws + 2 * M1F, 0, 24 * M1F * sizeof(float), stream);

  // all adj@x for all timesteps in one GEMM
  transpose1024<<<dim3(32, 32), dim3(32, 8), 0, stream>>>(xs, xTT);
  sgemm_adj<1><<<dim3(8, 8), 256, 0, stream>>>(adj, xTT, AX, 1024);

  for (int t = 0; t < T; ++t) {
    const float* AXt = AX + (size_t)t * R;
    // ---- layer 0 (C=64) ----
    gate_gemm<0><<<dim3(1, 512), 256, 0, stream>>>(AXt, 1, AH1, C1, Wg[0][0], bgv[0][0],
                                                   C1, ZB, nullptr, nullptr);
    gate_gemm<0><<<dim3(1, 512), 256, 0, stream>>>(AXt, 1, AH1, C1, Wg[0][1], bgv[0][1],
                                                   C1, RB, nullptr, nullptr);
    mul_inplace<<<2048, 256, 0, stream>>>(RB, h1, R * C1);
    sgemm_adj<0><<<dim3(32, 8), 256, 0, stream>>>(adj, RB, SCR, 4096);
    gate_gemm<1><<<dim3(1, 512), 256, 0, stream>>>(AXt, 1, SCR, C1, Wg[0][2], bgv[0][2],
                                                   C1, nullptr, ZB, h1);
    sgemm_adj<0><<<dim3(32, 8), 256, 0, stream>>>(adj, h1, AH1, 4096);
    // ---- layer 1 (C=128) ----
    gate_gemm<0><<<dim3(2, 512), 256, 0, stream>>>(AH1, C1, AH2, C2, Wg[1][0], bgv[1][0],
                                                   C2, ZB, nullptr, nullptr);
    gate_gemm<0><<<dim3(2, 512), 256, 0, stream>>>(AH1, C1, AH2, C2, Wg[1][1], bgv[1][1],
                                                   C2, RB, nullptr, nullptr);
    mul_inplace<<<2048, 256, 0, stream>>>(RB, h2, R * C2);
    sgemm_adj<0><<<dim3(64, 8), 256, 0, stream>>>(adj, RB, SCR, 8192);
    gate_gemm<1><<<dim3(2, 512), 256, 0, stream>>>(AH1, C1, SCR, C2, Wg[1][2], bgv[1][2],
                                                   C2, nullptr, ZB, h2);
    if (t + 1 < T)
      sgemm_adj<0><<<dim3(64, 8), 256, 0, stream>>>(adj, h2, AH2, 8192);
  }

  // dense heads
  build_xst<<<1024, 256, 0, stream>>>(h1, h2, XST);
  dense_partial<<<dim3(4, KCH, 2), 256, 0, stream>>>(XST, Wmu, Wlv, P);
  eps_kernel<<<64, 256, 0, stream>>>(EPS);
  final_kernel<<<64, 256, 0, stream>>>(P, bmu, blv, EPS, (float*)d_out);
}

// Round 2
// 4135.274 us; speedup vs baseline: 4.1353x; 4.1353x over previous
//
#include <hip/hip_runtime.h>
#include <math.h>

#define EPS_MODE 0

typedef unsigned short u16;
typedef short bf16x8 __attribute__((ext_vector_type(8)));
typedef float f32x4 __attribute__((ext_vector_type(4)));

static constexpr int T    = 16;
static constexpr int NND  = 1024;
static constexpr int C1   = 64;
static constexpr int C2   = 128;
static constexpr int RTOT = 65536;        // 64 b * 1024 n
static constexpr int KCH  = 384;          // dense split-K chunks
static constexpr int KCHUNK = 196608 / KCH;  // 512
static constexpr size_t MF = 1u << 20;

__device__ __forceinline__ u16 f2bf(float f) {
  unsigned u = __float_as_uint(f);
  unsigned r = (u + 0x7fffu + ((u >> 16) & 1u)) >> 16;
  return (u16)r;
}

__device__ __forceinline__ void gload16(const void* g, void* l) {
  __builtin_amdgcn_global_load_lds(
      (const __attribute__((address_space(1))) void*)g,
      (__attribute__((address_space(3))) void*)l, 16, 0, 0);
}

// ---------------- casts -------------------------------------------------------------
__global__ __launch_bounds__(256) void cast_bf16(const float* __restrict__ in,
                                                 u16* __restrict__ out, int n) {
  int i = (blockIdx.x * 256 + threadIdx.x) * 4;
  if (i < n) {
    float4 v = *reinterpret_cast<const float4*>(&in[i]);
    out[i + 0] = f2bf(v.x); out[i + 1] = f2bf(v.y);
    out[i + 2] = f2bf(v.z); out[i + 3] = f2bf(v.w);
  }
}

// ---------------- W transpose+cast: WT[col][k] --------------------------------------
__global__ __launch_bounds__(256) void prep_wt(const float* __restrict__ Wz0, const float* __restrict__ Wr0,
                                               const float* __restrict__ Wn0, const float* __restrict__ Wz1,
                                               const float* __restrict__ Wr1, const float* __restrict__ Wn1,
                                               u16* __restrict__ WzrT0, u16* __restrict__ WnT0,
                                               u16* __restrict__ WzrT1, u16* __restrict__ WnT1) {
  int seg = blockIdx.y;
  int idx = blockIdx.x * 256 + threadIdx.x;
  if (seg == 0) {        // [128][64] : z|r, h-part rows 1..64
    if (idx < 128 * 64) {
      int j = idx >> 6, k = idx & 63;
      float v = (j < 64) ? Wz0[(k + 1) * 64 + j] : Wr0[(k + 1) * 64 + (j - 64)];
      WzrT0[idx] = f2bf(v);
    }
  } else if (seg == 1) {  // [64][64]
    if (idx < 64 * 64) {
      int j = idx >> 6, k = idx & 63;
      WnT0[idx] = f2bf(Wn0[(k + 1) * 64 + j]);
    }
  } else if (seg == 2) {  // [256][192]
    if (idx < 256 * 192) {
      int j = idx / 192, k = idx % 192;
      float v = (j < 128) ? Wz1[k * 128 + j] : Wr1[k * 128 + (j - 128)];
      WzrT1[idx] = f2bf(v);
    }
  } else {                // [128][192]
    if (idx < 128 * 192) {
      int j = idx / 192, k = idx % 192;
      WnT1[idx] = f2bf(Wn1[k * 128 + j]);
    }
  }
}

// ---------------- adjacency MFMA GEMM -----------------------------------------------
// OUT[row][col] = sum_k adjB[row][k] * BT[col][k]   (1024 x ncols, K=1024)
// EPI 0: OUT bf16 gate layout [b][n][C]: idx ((b<<10)+row)*C + c, col=(b<<LOGC)+c
// EPI 1: OUT f32 AX layout [t][b][n]: idx (t<<16)+(b<<10)+row, col=(t<<6)+b
template <int EPI, int LOGC>
__global__ __launch_bounds__(256) void adj_mfma(const u16* __restrict__ A,
                                                const u16* __restrict__ BT,
                                                void* __restrict__ OUT) {
  __shared__ __align__(16) char lds[32768];
  int tid = threadIdx.x;
  int w = tid >> 6, lane = tid & 63;
  int row0 = blockIdx.y * 128, col0 = blockIdx.x * 128;
  int wm = w >> 1, wn = w & 1;
  f32x4 acc[4][4] = {};
  for (int k0 = 0; k0 < 1024; k0 += 64) {
#pragma unroll
    for (int q = 0; q < 4; ++q) {
      int row = q * 32 + w * 8 + (lane >> 3);
      gload16(A + (size_t)(row0 + row) * 1024 + k0 + (lane & 7) * 8,
              lds + q * 4096 + w * 1024);
    }
#pragma unroll
    for (int q = 0; q < 4; ++q) {
      int row = q * 32 + w * 8 + (lane >> 3);
      gload16(BT + (size_t)(col0 + row) * 1024 + k0 + (lane & 7) * 8,
              lds + 16384 + q * 4096 + w * 1024);
    }
    __syncthreads();
#pragma unroll
    for (int kk = 0; kk < 2; ++kk) {
      bf16x8 a[4], bb[4];
#pragma unroll
      for (int m = 0; m < 4; ++m)
        a[m] = *(const bf16x8*)(lds + (wm * 64 + m * 16 + (lane & 15)) * 128 + kk * 64 + (lane >> 4) * 16);
#pragma unroll
      for (int n = 0; n < 4; ++n)
        bb[n] = *(const bf16x8*)(lds + 16384 + (wn * 64 + n * 16 + (lane & 15)) * 128 + kk * 64 + (lane >> 4) * 16);
#pragma unroll
      for (int m = 0; m < 4; ++m)
#pragma unroll
        for (int n = 0; n < 4; ++n)
          acc[m][n] = __builtin_amdgcn_mfma_f32_16x16x32_bf16(a[m], bb[n], acc[m][n], 0, 0, 0);
    }
    __syncthreads();
  }
  if (EPI == 1) {
    float* O = (float*)OUT;
#pragma unroll
    for (int m = 0; m < 4; ++m)
#pragma unroll
      for (int n = 0; n < 4; ++n) {
        int col = col0 + wn * 64 + n * 16 + (lane & 15);
        int t = col >> 6, bbx = col & 63;
        int row = row0 + wm * 64 + m * 16 + ((lane >> 4) << 2);
        *(float4*)&O[((size_t)t << 16) + ((size_t)bbx << 10) + row] =
            *(float4*)&acc[m][n];
      }
  } else {
    u16* O = (u16*)OUT;
    constexpr int C = 1 << LOGC;
#pragma unroll
    for (int m = 0; m < 4; ++m)
#pragma unroll
      for (int n = 0; n < 4; ++n) {
        int col = col0 + wn * 64 + n * 16 + (lane & 15);
        int bbx = col >> LOGC, c = col & (C - 1);
#pragma unroll
        for (int j = 0; j < 4; ++j) {
          int row = row0 + wm * 64 + m * 16 + ((lane >> 4) << 2) + j;
          O[(((size_t)bbx << 10) + row) * C + c] = f2bf(acc[m][n][j]);
        }
      }
  }
}

// ---------------- gate MFMA GEMM ----------------------------------------------------
// rows r = b*1024+n (block rows share b), A = [A1 seg | A2 seg] bf16, W^T bf16 [NT][K]
// MODE 0 (zr): NT=2C: cols<C -> z=sigmoid -> ZB f32; cols>=C -> r=sigmoid, rh=r*h -> TOUT [b][c][n] bf16
// MODE 1 (n):  NT=C: n=tanh, h=(1-z)h+z*n -> hout f32 + TOUT [b][c][n] bf16
template <int WM, int WN, int C, int NK1, int NK, int MODE, int RK1>
__global__ __launch_bounds__(256) void gate_mfma(
    const u16* __restrict__ A1, const u16* __restrict__ A2,
    const u16* __restrict__ WT,
    const float* __restrict__ bias0, const float* __restrict__ bias1,
    const float* __restrict__ axv, const float* __restrict__ w0a,
    const float* __restrict__ w0b, const float* __restrict__ h,
    float* __restrict__ ZB, float* __restrict__ hout, u16* __restrict__ TOUT) {
  constexpr int MT = WM * 64, NT = WN * 64, K = NK * 64;
  constexpr int NB = 1024 / MT;
  constexpr int STAGE = MT * 128 + NT * 128;
  constexpr int TB = C * (MT + 8) * 2;
  constexpr int LDSZ = STAGE > TB ? STAGE : TB;
  __shared__ __align__(16) char lds[LDSZ];
  int tid = threadIdx.x;
  int w = tid >> 6, lane = tid & 63;
  int by = blockIdx.x;
  int b = by / NB, n0 = (by % NB) * MT;
  size_t row0 = ((size_t)b << 10) + n0;
  int wm = w / WN, wn = w % WN;
  f32x4 acc[4][4] = {};
  for (int s = 0; s < NK; ++s) {
    const u16* As; int astr, koff;
    if (s < NK1) { As = A1; astr = 64; koff = s * 64; }
    else         { As = A2; astr = 128; koff = (s - NK1) * 64; }
#pragma unroll
    for (int q = 0; q < MT / 32; ++q) {
      int row = q * 32 + w * 8 + (lane >> 3);
      gload16(As + (row0 + row) * astr + koff + (lane & 7) * 8,
              lds + q * 4096 + w * 1024);
    }
#pragma unroll
    for (int q = 0; q < NT / 32; ++q) {
      int row = q * 32 + w * 8 + (lane >> 3);
      gload16(WT + (size_t)row * K + s * 64 + (lane & 7) * 8,
              lds + MT * 128 + q * 4096 + w * 1024);
    }
    __syncthreads();
#pragma unroll
    for (int kk = 0; kk < 2; ++kk) {
      bf16x8 a[4], bb[4];
#pragma unroll
      for (int m = 0; m < 4; ++m)
        a[m] = *(const bf16x8*)(lds + (wm * 64 + m * 16 + (lane & 15)) * 128 + kk * 64 + (lane >> 4) * 16);
#pragma unroll
      for (int n = 0; n < 4; ++n)
        bb[n] = *(const bf16x8*)(lds + MT * 128 + (wn * 64 + n * 16 + (lane & 15)) * 128 + kk * 64 + (lane >> 4) * 16);
#pragma unroll
      for (int m = 0; m < 4; ++m)
#pragma unroll
        for (int n = 0; n < 4; ++n)
          acc[m][n] = __builtin_amdgcn_mfma_f32_16x16x32_bf16(a[m], bb[n], acc[m][n], 0, 0, 0);
    }
    __syncthreads();
  }
  // epilogue
  float axr[4][4];
  if (RK1) {
#pragma unroll
    for (int m = 0; m < 4; ++m) {
      float4 v = *(const float4*)&axv[row0 + wm * 64 + m * 16 + ((lane >> 4) << 2)];
      axr[m][0] = v.x; axr[m][1] = v.y; axr[m][2] = v.z; axr[m][3] = v.w;
    }
  }
  u16* Tb = (u16*)lds;
  if (MODE == 0) {
    bool zwave = (wn * 64) < C;
    int cloc = wn * 64 - (zwave ? 0 : C);
#pragma unroll
    for (int m = 0; m < 4; ++m)
#pragma unroll
      for (int n = 0; n < 4; ++n)
#pragma unroll
        for (int j = 0; j < 4; ++j) {
          int c = cloc + n * 16 + (lane & 15);
          int rl = wm * 64 + m * 16 + ((lane >> 4) << 2) + j;
          size_t rr = row0 + rl;
          float g = acc[m][n][j] + (zwave ? bias0 : bias1)[c];
          if (RK1) g += axr[m][j] * (zwave ? w0a : w0b)[c];
          float sg = 1.f / (1.f + expf(-g));
          if (zwave) {
            ZB[rr * C + c] = sg;
          } else {
            float rh = sg * h[rr * C + c];
            Tb[c * (MT + 8) + rl] = f2bf(rh);
          }
        }
  } else {
#pragma unroll
    for (int m = 0; m < 4; ++m)
#pragma unroll
      for (int n = 0; n < 4; ++n)
#pragma unroll
        for (int j = 0; j < 4; ++j) {
          int c = wn * 64 + n * 16 + (lane & 15);
          int rl = wm * 64 + m * 16 + ((lane >> 4) << 2) + j;
          size_t rr = row0 + rl;
          float g = acc[m][n][j] + bias0[c];
          if (RK1) g += axr[m][j] * w0a[c];
          float nn = tanhf(g);
          float z = ZB[rr * C + c], hold = h[rr * C + c];
          float hn = (1.f - z) * hold + z * nn;
          hout[rr * C + c] = hn;
          Tb[c * (MT + 8) + rl] = f2bf(hn);
        }
  }
  __syncthreads();
  // cooperative transposed write: TOUT[(b*C+c)*1024 + n0 + pos]
  constexpr int CH = C * MT / 8;
  for (int ch = tid; ch < CH; ch += 256) {
    int c = ch / (MT / 8), pos = (ch % (MT / 8)) * 8;
    int4 v = *(const int4*)(Tb + c * (MT + 8) + pos);
    *(int4*)&TOUT[(((size_t)(b * C + c)) << 10) + n0 + pos] = v;
  }
}

// ---------------- build XST[k=n*192+c][b] from h1 [b][n][64], h2 [b][n][128] --------
__global__ __launch_bounds__(256) void build_xst(const float* __restrict__ h1,
                                                 const float* __restrict__ h2,
                                                 float* __restrict__ xst) {
  int n = blockIdx.x;
  __shared__ float t1[64][65];
  __shared__ float t2[128][65];
  int tid = threadIdx.x;
  {
    int c = tid & 63;
#pragma unroll
    for (int i = 0; i < 16; ++i) {
      int b = (tid >> 6) + i * 4;
      t1[c][b] = h1[(((size_t)b << 10) + n) * 64 + c];
    }
  }
  {
    int c = tid & 127;
#pragma unroll
    for (int i = 0; i < 32; ++i) {
      int b = (tid >> 7) + i * 2;
      t2[c][b] = h2[(((size_t)b << 10) + n) * 128 + c];
    }
  }
  __syncthreads();
#pragma unroll
  for (int i = 0; i < 48; ++i) {
    int c = (tid >> 6) + i * 4, b = tid & 63;
    xst[((size_t)n * 192 + c) * 64 + b] = (c < 64) ? t1[c][b] : t2[c - 64][b];
  }
}

// ---------------- dense split-K partials --------------------------------------------
__global__ __launch_bounds__(256) void dense_partial(const float* __restrict__ xst,
                                                     const float* __restrict__ Wmu,
                                                     const float* __restrict__ Wlv,
                                                     float* __restrict__ P) {
  int ot = blockIdx.x, ch = blockIdx.y, mat = blockIdx.z;
  const float* W = mat ? Wlv : Wmu;
  __shared__ float As[16][64];
  __shared__ float Ws[16][64];
  int tid = threadIdx.x;
  int tx = tid & 15, ty = tid >> 4;
  int kk = tid >> 4, q = tid & 15;
  float acc[4][4] = {};
  int kend = ch * KCHUNK + KCHUNK;
  for (int k0 = ch * KCHUNK; k0 < kend; k0 += 16) {
    *(float4*)&As[kk][q * 4] = *(const float4*)&xst[(size_t)(k0 + kk) * 64 + q * 4];
    *(float4*)&Ws[kk][q * 4] = *(const float4*)&W[(size_t)(k0 + kk) * 256 + ot * 64 + q * 4];
    __syncthreads();
#pragma unroll
    for (int k = 0; k < 16; ++k) {
      float a[4], b[4];
      *(float4*)a = *(const float4*)&As[k][ty * 4];
      *(float4*)b = *(const float4*)&Ws[k][tx * 4];
#pragma unroll
      for (int i = 0; i < 4; ++i)
#pragma unroll
        for (int j = 0; j < 4; ++j) acc[i][j] += a[i] * b[j];
    }
    __syncthreads();
  }
#pragma unroll
  for (int i = 0; i < 4; ++i)
#pragma unroll
    for (int j = 0; j < 4; ++j) {
      int brow = ty * 4 + i, o = ot * 64 + tx * 4 + j;
      P[(((size_t)mat * KCH + ch) * 64 + brow) * 256 + o] = acc[i][j];
    }
}

// ---------------- threefry / eps ----------------------------------------------------
__device__ __forceinline__ unsigned rotl32(unsigned v, int s) {
  return (v << s) | (v >> (32 - s));
}
__device__ void threefry(unsigned k0, unsigned k1, unsigned x0, unsigned x1,
                         unsigned& o0, unsigned& o1) {
  unsigned ks2 = k0 ^ k1 ^ 0x1BD11BDAu;
  unsigned a = x0 + k0, b = x1 + k1;
#define TF_RND(rot) { a += b; b = rotl32(b, rot); b ^= a; }
  TF_RND(13) TF_RND(15) TF_RND(26) TF_RND(6)
  a += k1; b += ks2 + 1u;
  TF_RND(17) TF_RND(29) TF_RND(16) TF_RND(24)
  a += ks2; b += k0 + 2u;
  TF_RND(13) TF_RND(15) TF_RND(26) TF_RND(6)
  a += k0; b += k1 + 3u;
  TF_RND(17) TF_RND(29) TF_RND(16) TF_RND(24)
  a += k1; b += ks2 + 4u;
  TF_RND(13) TF_RND(15) TF_RND(26) TF_RND(6)
  a += ks2; b += k0 + 5u;
#undef TF_RND
  o0 = a; o1 = b;
}

__device__ float u32_to_normal(unsigned bits) {
  unsigned fb = (bits >> 9) | 0x3F800000u;
  float f = __uint_as_float(fb) - 1.0f;
  const float lo = -0.99999994f;
  float u = f * 2.0f + lo;
  u = fmaxf(lo, u);
  float w = -log1pf(-u * u);
  float p;
  if (w < 5.0f) {
    w -= 2.5f;
    p = 2.81022636e-08f;
    p = fmaf(p, w, 3.43273939e-07f);
    p = fmaf(p, w, -3.5233877e-06f);
    p = fmaf(p, w, -4.39150654e-06f);
    p = fmaf(p, w, 0.00021858087f);
    p = fmaf(p, w, -0.00125372503f);
    p = fmaf(p, w, -0.00417768164f);
    p = fmaf(p, w, 0.246640727f);
    p = fmaf(p, w, 1.50140941f);
  } else {
    w = sqrtf(w) - 3.0f;
    p = -0.000200214257f;
    p = fmaf(p, w, 0.000100950558f);
    p = fmaf(p, w, 0.00134934322f);
    p = fmaf(p, w, -0.00367342844f);
    p = fmaf(p, w, 0.00573950773f);
    p = fmaf(p, w, -0.0076224613f);
    p = fmaf(p, w, 0.00943887047f);
    p = fmaf(p, w, 1.00167406f);
    p = fmaf(p, w, 2.83297682f);
  }
  return 1.41421354f * (p * u);
}

__global__ __launch_bounds__(256) void eps_kernel(float* __restrict__ eps) {
  int b = blockIdx.x;
  int o = threadIdx.x;
  unsigned k0, k1;
  threefry(0u, 0u, 0u, 1234u, k0, k1);
  float s = 0.f;
  for (int smp = 0; smp < 50; ++smp) {
    unsigned idx = ((unsigned)smp * 64u + (unsigned)b) * 256u + (unsigned)o;
    unsigned o0, o1, bits;
#if EPS_MODE == 0
    threefry(k0, k1, 0u, idx, o0, o1);
    bits = o0 ^ o1;
#else
    unsigned pp = idx % 409600u, half = idx / 409600u;
    threefry(k0, k1, pp, pp + 409600u, o0, o1);
    bits = half ? o1 : o0;
#endif
    s += u32_to_normal(bits);
  }
  eps[b * 256 + o] = s / 50.0f;
}

// ---------------- final reduce + heads + reparam ------------------------------------
__global__ __launch_bounds__(256) void final_kernel(const float* __restrict__ P,
                                                    const float* __restrict__ bmu,
                                                    const float* __restrict__ blv,
                                                    const float* __restrict__ eps,
                                                    float* __restrict__ out) {
  int b = blockIdx.x, o = threadIdx.x;
  float smu = 0.f, slv = 0.f;
  for (int ch = 0; ch < KCH; ++ch) {
    smu += P[(((size_t)0 * KCH + ch) * 64 + b) * 256 + o];
    slv += P[(((size_t)1 * KCH + ch) * 64 + b) * 256 + o];
  }
  float mu = 1.f / (1.f + expf(-(smu + bmu[o])));
  float lv = 1.f / (1.f + expf(-(slv + blv[o])));
  float z = mu + eps[b * 256 + o] * expf(0.5f * lv);
  out[b * 256 + o] = z;
  out[16384 + b * 256 + o] = mu;
  out[32768 + b * 256 + o] = lv;
}

// ------------------------------------------------------------------------------------
extern "C" void kernel_launch(void* const* d_in, const int* in_sizes, int n_in,
                              void* d_out, int out_size, void* d_ws, size_t ws_size,
                              hipStream_t stream) {
  (void)in_sizes; (void)n_in; (void)out_size; (void)ws_size;
  const float* xs  = (const float*)d_in[0];
  const float* adj = (const float*)d_in[1];
  const float* Wz0 = (const float*)d_in[2];  const float* bz0 = (const float*)d_in[3];
  const float* Wr0 = (const float*)d_in[4];  const float* br0 = (const float*)d_in[5];
  const float* Wn0 = (const float*)d_in[6];  const float* bn0 = (const float*)d_in[7];
  const float* Wz1 = (const float*)d_in[8];  const float* bz1 = (const float*)d_in[9];
  const float* Wr1 = (const float*)d_in[10]; const float* br1 = (const float*)d_in[11];
  const float* Wn1 = (const float*)d_in[12]; const float* bn1 = (const float*)d_in[13];
  const float* Wmu = (const float*)d_in[14]; const float* bmu = (const float*)d_in[15];
  const float* Wlv = (const float*)d_in[16]; const float* blv = (const float*)d_in[17];

  float* ws = (float*)d_ws;
  float* h1    = ws;                         // [b][n][64] f32  (4MF)
  float* h2    = ws + 4 * MF;                // [b][n][128] f32 (8MF)
  u16*  adjB   = (u16*)(ws + 12 * MF);       // [1024][1024]
  u16*  xsB    = (u16*)(ws + 12 * MF + MF / 2);  // [(t,b)][n]
  u16*  WTb    = (u16*)(ws + 13 * MF);
  float* AXv   = ws + 13 * MF + MF / 4;      // [t][b][n] f32 (1MF)
  u16*  h1T    = (u16*)(ws + 14 * MF + MF / 4);  // [b][c64][n]
  u16*  h2T    = (u16*)(ws + 16 * MF + MF / 4);  // [b][c128][n]
  u16*  AH1    = (u16*)(ws + 20 * MF + MF / 4);  // [b][n][64]
  u16*  AH2    = (u16*)(ws + 22 * MF + MF / 4);  // [b][n][128]
  u16*  ANB    = (u16*)(ws + 26 * MF + MF / 4);  // adj@(r*h) [b][n][C]
  u16*  RHB    = (u16*)(ws + 30 * MF + MF / 4);  // r*h  [b][c][n]
  float* ZB    = ws + 34 * MF + MF / 4;      // z f32 [r][C] (8MF)
  float* XST   = ws + 12 * MF;               // post-loop alias (12.6MF)
  float* P     = ws + 25 * MF;               // post-loop alias (12.6MF)
  float* EPS   = ws + 42 * MF + MF / 2;

  u16* WzrT0 = WTb;
  u16* WnT0  = WTb + 8192;
  u16* WzrT1 = WTb + 12288;
  u16* WnT1  = WTb + 61440;

  // zero h1,h2 and AH1,AH2
  hipMemsetAsync(ws, 0, 12 * MF * sizeof(float), stream);
  hipMemsetAsync(ws + 20 * MF + MF / 4, 0, 6 * MF * sizeof(float), stream);

  // setup casts
  cast_bf16<<<1024, 256, 0, stream>>>(adj, adjB, 1 << 20);
  cast_bf16<<<1024, 256, 0, stream>>>(xs, xsB, 1 << 20);
  prep_wt<<<dim3(192, 4), 256, 0, stream>>>(Wz0, Wr0, Wn0, Wz1, Wr1, Wn1,
                                            WzrT0, WnT0, WzrT1, WnT1);

  // AX[t][b][n] = adj @ x_t for all t in one GEMM (cols = (t,b))
  adj_mfma<1, 0><<<dim3(8, 8), 256, 0, stream>>>(adjB, xsB, AXv);

  for (int t = 0; t < T; ++t) {
    const float* AXt = AXv + (size_t)t * 65536;
    // ---- layer 0 (C=64) ----
    gate_mfma<2, 2, 64, 1, 1, 0, 1><<<512, 256, 0, stream>>>(
        AH1, nullptr, WzrT0, bz0, br0, AXt, Wz0, Wr0, h1, ZB, nullptr, RHB);
    adj_mfma<0, 6><<<dim3(32, 8), 256, 0, stream>>>(adjB, RHB, ANB);
    gate_mfma<4, 1, 64, 1, 1, 1, 1><<<256, 256, 0, stream>>>(
        ANB, nullptr, WnT0, bn0, nullptr, AXt, Wn0, nullptr, h1, ZB, h1, h1T);
    adj_mfma<0, 6><<<dim3(32, 8), 256, 0, stream>>>(adjB, h1T, AH1);
    // ---- layer 1 (C=128) ----
    gate_mfma<1, 4, 128, 1, 3, 0, 0><<<1024, 256, 0, stream>>>(
        AH1, AH2, WzrT1, bz1, br1, nullptr, nullptr, nullptr, h2, ZB, nullptr, RHB);
    adj_mfma<0, 7><<<dim3(64, 8), 256, 0, stream>>>(adjB, RHB, ANB);
    gate_mfma<2, 2, 128, 1, 3, 1, 0><<<512, 256, 0, stream>>>(
        AH1, ANB, WnT1, bn1, nullptr, nullptr, nullptr, nullptr, h2, ZB, h2, h2T);
    if (t + 1 < T)
      adj_mfma<0, 7><<<dim3(64, 8), 256, 0, stream>>>(adjB, h2T, AH2);
  }

  // dense heads
  build_xst<<<1024, 256, 0, stream>>>(h1, h2, XST);
  dense_partial<<<dim3(4, KCH, 2), 256, 0, stream>>>(XST, Wmu, Wlv, P);
  eps_kernel<<<64, 256, 0, stream>>>(EPS);
  final_kernel<<<64, 256, 0, stream>>>(P, bmu, blv, EPS, (float*)d_out);
}

// Round 3
// 3304.397 us; speedup vs baseline: 5.1751x; 1.2514x over previous
//
#include <hip/hip_runtime.h>
#include <math.h>

#define EPS_MODE 0

typedef unsigned short u16;
typedef short bf16x8 __attribute__((ext_vector_type(8)));
typedef float f32x4 __attribute__((ext_vector_type(4)));
typedef u16 u16x4 __attribute__((ext_vector_type(4)));
typedef u16 u16x8 __attribute__((ext_vector_type(8)));

static constexpr int T = 16;
static constexpr size_t MF = 1u << 20;

__device__ __forceinline__ u16 f2bf(float f) {
  unsigned u = __float_as_uint(f);
  unsigned r = (u + 0x7fffu + ((u >> 16) & 1u)) >> 16;
  return (u16)r;
}
__device__ __forceinline__ float bf2f(u16 h) {
  return __uint_as_float(((unsigned)h) << 16);
}
__device__ __forceinline__ void gload16(const void* g, void* l) {
  __builtin_amdgcn_global_load_lds(
      (const __attribute__((address_space(1))) void*)g,
      (__attribute__((address_space(3))) void*)l, 16, 0, 0);
}

// ---------------- casts -------------------------------------------------------------
__global__ __launch_bounds__(256) void cast_bf16(const float* __restrict__ in,
                                                 u16* __restrict__ out, int n) {
  int i = (blockIdx.x * 256 + threadIdx.x) * 4;
  if (i < n) {
    float4 v = *reinterpret_cast<const float4*>(&in[i]);
    out[i + 0] = f2bf(v.x); out[i + 1] = f2bf(v.y);
    out[i + 2] = f2bf(v.z); out[i + 3] = f2bf(v.w);
  }
}

// ---------------- W transpose+cast: WT[col][k] --------------------------------------
__global__ __launch_bounds__(256) void prep_wt(const float* __restrict__ Wz0, const float* __restrict__ Wr0,
                                               const float* __restrict__ Wn0, const float* __restrict__ Wz1,
                                               const float* __restrict__ Wr1, const float* __restrict__ Wn1,
                                               u16* __restrict__ WzrT0, u16* __restrict__ WnT0,
                                               u16* __restrict__ WzrT1, u16* __restrict__ WnT1) {
  int seg = blockIdx.y;
  int idx = blockIdx.x * 256 + threadIdx.x;
  if (seg == 0) {        // [128 out][64 k] : z|r, h-part rows 1..64
    if (idx < 128 * 64) {
      int j = idx >> 6, k = idx & 63;
      float v = (j < 64) ? Wz0[(k + 1) * 64 + j] : Wr0[(k + 1) * 64 + (j - 64)];
      WzrT0[idx] = f2bf(v);
    }
  } else if (seg == 1) {  // [64][64]
    if (idx < 64 * 64) {
      int j = idx >> 6, k = idx & 63;
      WnT0[idx] = f2bf(Wn0[(k + 1) * 64 + j]);
    }
  } else if (seg == 2) {  // [256][192]
    if (idx < 256 * 192) {
      int j = idx / 192, k = idx % 192;
      float v = (j < 128) ? Wz1[k * 128 + j] : Wr1[k * 128 + (j - 128)];
      WzrT1[idx] = f2bf(v);
    }
  } else {                // [128][192]
    if (idx < 128 * 192) {
      int j = idx / 192, k = idx % 192;
      WnT1[idx] = f2bf(Wn1[k * 128 + j]);
    }
  }
}

// ---------------- plain adjacency MFMA GEMM -----------------------------------------
// OUT[row][col] = sum_k A[row][k] * BT[col][k]   (1024 x ncols, K=1024)
// EPI 0: OUT bf16 [b][n][C]: col=(b<<LOGC)+c
// EPI 1: OUT f32 AX [t][b][n]: col=(t<<6)+b
template <int EPI, int LOGC>
__global__ __launch_bounds__(256) void adj_mfma(const u16* __restrict__ A,
                                                const u16* __restrict__ BT,
                                                void* __restrict__ OUT) {
  __shared__ __align__(16) char lds[32768];
  int tid = threadIdx.x;
  int w = tid >> 6, lane = tid & 63;
  int row0 = blockIdx.y * 128, col0 = blockIdx.x * 128;
  int wm = w >> 1, wn = w & 1;
  f32x4 acc[4][4] = {};
  for (int k0 = 0; k0 < 1024; k0 += 64) {
#pragma unroll
    for (int q = 0; q < 4; ++q) {
      int row = q * 32 + w * 8 + (lane >> 3);
      gload16(A + (size_t)(row0 + row) * 1024 + k0 + (lane & 7) * 8,
              lds + q * 4096 + w * 1024);
    }
#pragma unroll
    for (int q = 0; q < 4; ++q) {
      int row = q * 32 + w * 8 + (lane >> 3);
      gload16(BT + (size_t)(col0 + row) * 1024 + k0 + (lane & 7) * 8,
              lds + 16384 + q * 4096 + w * 1024);
    }
    __syncthreads();
#pragma unroll
    for (int kk = 0; kk < 2; ++kk) {
      bf16x8 a[4], bb[4];
#pragma unroll
      for (int m = 0; m < 4; ++m)
        a[m] = *(const bf16x8*)(lds + (wm * 64 + m * 16 + (lane & 15)) * 128 + kk * 64 + (lane >> 4) * 16);
#pragma unroll
      for (int n = 0; n < 4; ++n)
        bb[n] = *(const bf16x8*)(lds + 16384 + (wn * 64 + n * 16 + (lane & 15)) * 128 + kk * 64 + (lane >> 4) * 16);
#pragma unroll
      for (int m = 0; m < 4; ++m)
#pragma unroll
        for (int n = 0; n < 4; ++n)
          acc[m][n] = __builtin_amdgcn_mfma_f32_16x16x32_bf16(a[m], bb[n], acc[m][n], 0, 0, 0);
    }
    __syncthreads();
  }
  if (EPI == 1) {
    float* O = (float*)OUT;
#pragma unroll
    for (int m = 0; m < 4; ++m)
#pragma unroll
      for (int n = 0; n < 4; ++n) {
        int col = col0 + wn * 64 + n * 16 + (lane & 15);
        int t = col >> 6, bbx = col & 63;
        int row = row0 + wm * 64 + m * 16 + ((lane >> 4) << 2);
        *(float4*)&O[((size_t)t << 16) + ((size_t)bbx << 10) + row] = *(float4*)&acc[m][n];
      }
  } else {
    u16* O = (u16*)OUT;
    constexpr int C = 1 << LOGC;
#pragma unroll
    for (int m = 0; m < 4; ++m)
#pragma unroll
      for (int n = 0; n < 4; ++n) {
        int col = col0 + wn * 64 + n * 16 + (lane & 15);
        int bbx = col >> LOGC, c = col & (C - 1);
#pragma unroll
        for (int j = 0; j < 4; ++j) {
          int row = row0 + wm * 64 + m * 16 + ((lane >> 4) << 2) + j;
          O[(((size_t)bbx << 10) + row) * C + c] = f2bf(acc[m][n][j]);
        }
      }
  }
}

// ---------------- fused adj@(r*h) + n-gate + GRU update -----------------------------
// main: AN[row n][col (b,c)] = adj @ rhT ; then n = tanh(AN.Wn + x-part + bias);
// h = (1-z)h + z*n written in place to hT [b][c][n] bf16.
template <int C, int RK1>
__global__ __launch_bounds__(256) void adj_ngate(
    const u16* __restrict__ A, const u16* __restrict__ BT,
    const u16* __restrict__ WnT, const float* __restrict__ bias,
    const float* __restrict__ axv, const float* __restrict__ wx,
    const u16* __restrict__ AH1, const u16* __restrict__ zT,
    u16* __restrict__ hT) {
  constexpr int LOGC = (C == 64) ? 6 : 7;
  constexpr int KW = (C == 64) ? 64 : 192;
  constexpr int KKAN = C / 32;
  __shared__ __align__(16) char lds[136 * 128 * 2];  // 34816: staging(32KB) then ANt
  int tid = threadIdx.x;
  int w = tid >> 6, lane = tid & 63;
  int row0 = blockIdx.y * 128, col0 = blockIdx.x * 128;
  int wm = w >> 1, wn = w & 1;
  f32x4 acc[4][4] = {};
  for (int k0 = 0; k0 < 1024; k0 += 64) {
#pragma unroll
    for (int q = 0; q < 4; ++q) {
      int row = q * 32 + w * 8 + (lane >> 3);
      gload16(A + (size_t)(row0 + row) * 1024 + k0 + (lane & 7) * 8,
              lds + q * 4096 + w * 1024);
    }
#pragma unroll
    for (int q = 0; q < 4; ++q) {
      int row = q * 32 + w * 8 + (lane >> 3);
      gload16(BT + (size_t)(col0 + row) * 1024 + k0 + (lane & 7) * 8,
              lds + 16384 + q * 4096 + w * 1024);
    }
    __syncthreads();
#pragma unroll
    for (int kk = 0; kk < 2; ++kk) {
      bf16x8 a[4], bb[4];
#pragma unroll
      for (int m = 0; m < 4; ++m)
        a[m] = *(const bf16x8*)(lds + (wm * 64 + m * 16 + (lane & 15)) * 128 + kk * 64 + (lane >> 4) * 16);
#pragma unroll
      for (int n = 0; n < 4; ++n)
        bb[n] = *(const bf16x8*)(lds + 16384 + (wn * 64 + n * 16 + (lane & 15)) * 128 + kk * 64 + (lane >> 4) * 16);
#pragma unroll
      for (int m = 0; m < 4; ++m)
#pragma unroll
        for (int n = 0; n < 4; ++n)
          acc[m][n] = __builtin_amdgcn_mfma_f32_16x16x32_bf16(a[m], bb[n], acc[m][n], 0, 0, 0);
    }
    __syncthreads();
  }
  // acc -> ANt bf16, stride 136 u16 (272B rows: 16B-aligned, 4-bank shift)
  u16* ANt = (u16*)lds;
#pragma unroll
  for (int m = 0; m < 4; ++m)
#pragma unroll
    for (int n = 0; n < 4; ++n) {
      int cl = wn * 64 + n * 16 + (lane & 15);
      int rl = wm * 64 + m * 16 + ((lane >> 4) << 2);
#pragma unroll
      for (int j = 0; j < 4; ++j)
        ANt[(rl + j) * 136 + cl] = f2bf(acc[m][n][j]);
    }
  __syncthreads();
  // gate phase: wave roles
  int arow0 = (w >> 1) * 64;
  int half = w & 1;
  int b0 = col0 >> LOGC;
  int out0 = (C == 64) ? 0 : half * 64;
  int kbase = (C == 64) ? half * 64 : 0;
  int b_eff = (C == 64) ? (b0 + half) : b0;
  constexpr int WOFF = (C == 64) ? 0 : 64;  // AN k-offset in WnT rows
  f32x4 acc2[4][4] = {};
#pragma unroll
  for (int kk = 0; kk < KKAN; ++kk) {
    bf16x8 a[4], bb[4];
    int ka = kbase + kk * 32 + (lane >> 4) * 8;
#pragma unroll
    for (int m = 0; m < 4; ++m)
      a[m] = *(const bf16x8*)&ANt[(arow0 + m * 16 + (lane & 15)) * 136 + ka];
#pragma unroll
    for (int n = 0; n < 4; ++n)
      bb[n] = *(const bf16x8*)&WnT[(size_t)(out0 + n * 16 + (lane & 15)) * KW + WOFF + kk * 32 + (lane >> 4) * 8];
#pragma unroll
    for (int m = 0; m < 4; ++m)
#pragma unroll
      for (int n = 0; n < 4; ++n)
        acc2[m][n] = __builtin_amdgcn_mfma_f32_16x16x32_bf16(a[m], bb[n], acc2[m][n], 0, 0, 0);
  }
  if (C == 128) {  // + AH1 (x) part, K=64
#pragma unroll
    for (int kk = 0; kk < 2; ++kk) {
      bf16x8 a[4], bb[4];
#pragma unroll
      for (int m = 0; m < 4; ++m)
        a[m] = *(const bf16x8*)&AH1[(((size_t)b0 << 10) + row0 + arow0 + m * 16 + (lane & 15)) * 64 + kk * 32 + (lane >> 4) * 8];
#pragma unroll
      for (int n = 0; n < 4; ++n)
        bb[n] = *(const bf16x8*)&WnT[(size_t)(out0 + n * 16 + (lane & 15)) * 192 + kk * 32 + (lane >> 4) * 8];
#pragma unroll
      for (int m = 0; m < 4; ++m)
#pragma unroll
        for (int n = 0; n < 4; ++n)
          acc2[m][n] = __builtin_amdgcn_mfma_f32_16x16x32_bf16(a[m], bb[n], acc2[m][n], 0, 0, 0);
    }
  }
  // epilogue: n=tanh, h=(1-z)h+z*n, in-place hT
#pragma unroll
  for (int m = 0; m < 4; ++m) {
    float ax4[4];
    if (RK1) {
      float4 v = *(const float4*)&axv[((size_t)b_eff << 10) + row0 + arow0 + m * 16 + ((lane >> 4) << 2)];
      ax4[0] = v.x; ax4[1] = v.y; ax4[2] = v.z; ax4[3] = v.w;
    }
#pragma unroll
    for (int n = 0; n < 4; ++n) {
      int cp = out0 + n * 16 + (lane & 15);
      int grow = arow0 + m * 16 + ((lane >> 4) << 2);
      size_t idx = (((size_t)b_eff << LOGC) + cp) * 1024 + row0 + grow;
      u16x4 zv = *(const u16x4*)&zT[idx];
      u16x4 hv = *(const u16x4*)&hT[idx];
      u16x4 pk;
#pragma unroll
      for (int j = 0; j < 4; ++j) {
        float g = acc2[m][n][j] + bias[cp];
        if (RK1) g += ax4[j] * wx[cp];
        float nv = tanhf(g);
        float z = bf2f(zv[j]), ho = bf2f(hv[j]);
        pk[j] = f2bf((1.f - z) * ho + z * nv);
      }
      *(u16x4*)&hT[idx] = pk;
    }
  }
}

// ---------------- zr gate GEMM: z/r = sigmoid(.), emits zT and rhT=r*h (bf16, ^T) ---
template <int WM, int WN, int C, int NK1, int NK, int RK1>
__global__ __launch_bounds__(256) void gate_zr(
    const u16* __restrict__ A1, const u16* __restrict__ A2,
    const u16* __restrict__ WT, const float* __restrict__ bz,
    const float* __restrict__ br, const float* __restrict__ axv,
    const float* __restrict__ wxz, const float* __restrict__ wxr,
    const u16* __restrict__ hT, u16* __restrict__ zTo, u16* __restrict__ rhTo) {
  constexpr int MT = WM * 64, NT = WN * 64, K = NK * 64;
  constexpr int NB = 1024 / MT;
  __shared__ __align__(16) char lds[MT * 128 + NT * 128];
  int tid = threadIdx.x;
  int w = tid >> 6, lane = tid & 63;
  int by = blockIdx.x;
  int b = by / NB, n0 = (by % NB) * MT;
  size_t row0 = ((size_t)b << 10) + n0;
  int wm = w / WN, wn = w % WN;
  f32x4 acc[4][4] = {};
  for (int s = 0; s < NK; ++s) {
    const u16* As; int astr, koff;
    if (s < NK1) { As = A1; astr = 64; koff = s * 64; }
    else         { As = A2; astr = 128; koff = (s - NK1) * 64; }
#pragma unroll
    for (int q = 0; q < MT / 32; ++q) {
      int row = q * 32 + w * 8 + (lane >> 3);
      gload16(As + (row0 + row) * astr + koff + (lane & 7) * 8,
              lds + q * 4096 + w * 1024);
    }
#pragma unroll
    for (int q = 0; q < NT / 32; ++q) {
      int row = q * 32 + w * 8 + (lane >> 3);
      gload16(WT + (size_t)row * K + s * 64 + (lane & 7) * 8,
              lds + MT * 128 + q * 4096 + w * 1024);
    }
    __syncthreads();
#pragma unroll
    for (int kk = 0; kk < 2; ++kk) {
      bf16x8 a[4], bb[4];
#pragma unroll
      for (int m = 0; m < 4; ++m)
        a[m] = *(const bf16x8*)(lds + (wm * 64 + m * 16 + (lane & 15)) * 128 + kk * 64 + (lane >> 4) * 16);
#pragma unroll
      for (int n = 0; n < 4; ++n)
        bb[n] = *(const bf16x8*)(lds + MT * 128 + (wn * 64 + n * 16 + (lane & 15)) * 128 + kk * 64 + (lane >> 4) * 16);
#pragma unroll
      for (int m = 0; m < 4; ++m)
#pragma unroll
        for (int n = 0; n < 4; ++n)
          acc[m][n] = __builtin_amdgcn_mfma_f32_16x16x32_bf16(a[m], bb[n], acc[m][n], 0, 0, 0);
    }
    __syncthreads();
  }
#pragma unroll
  for (int m = 0; m < 4; ++m) {
    float ax4[4];
    if (RK1) {
      float4 v = *(const float4*)&axv[row0 + wm * 64 + m * 16 + ((lane >> 4) << 2)];
      ax4[0] = v.x; ax4[1] = v.y; ax4[2] = v.z; ax4[3] = v.w;
    }
#pragma unroll
    for (int n = 0; n < 4; ++n) {
      int cp = wn * 64 + n * 16 + (lane & 15);
      bool iz = cp < C;
      int c = iz ? cp : cp - C;
      int rl = wm * 64 + m * 16 + ((lane >> 4) << 2);
      size_t idx = (((size_t)b * C + c) << 10) + n0 + rl;
      u16x4 hv;
      if (!iz) hv = *(const u16x4*)&hT[idx];
      u16x4 pk;
#pragma unroll
      for (int j = 0; j < 4; ++j) {
        float g = acc[m][n][j] + (iz ? bz : br)[c];
        if (RK1) g += ax4[j] * (iz ? wxz : wxr)[c];
        float sg = 1.f / (1.f + expf(-g));
        pk[j] = iz ? f2bf(sg) : f2bf(sg * bf2f(hv[j]));
      }
      *(u16x4*)&(iz ? zTo : rhTo)[idx] = pk;
    }
  }
}

// ---------------- dense head: P[mat][ch][64 b][256 o] partials ----------------------
// contraction order k' = c*1024 + n; A = hT (bf16, contiguous); W rows gathered.
__global__ __launch_bounds__(256) void dense_gemm(const u16* __restrict__ h1T,
                                                  const u16* __restrict__ h2T,
                                                  const float* __restrict__ Wmu,
                                                  const float* __restrict__ Wlv,
                                                  float* __restrict__ P) {
  int ch = blockIdx.x, mat = blockIdx.y;
  const float* W = mat ? Wlv : Wmu;
  __shared__ float As[64][36];
  __shared__ float Ws[32][260];
  int tid = threadIdx.x;
  int k0 = ch * 512;
  bool is1 = ch < 128;
  const u16* hs = is1 ? h1T : h2T;
  int kloc = is1 ? k0 : (k0 - 65536);
  int bstr = is1 ? 65536 : 131072;
  int wofs = is1 ? 0 : 64;
  int ab = tid >> 2, aks = (tid & 3) * 8;
  int wkk = tid >> 3, woq = (tid & 7) * 32;
  int tx = tid & 15, ty = tid >> 4;
  float acc[4][16] = {};
  u16x8 av;
  float4 wv[8];
  int ka = kloc;
  // issue 0
  av = *(const u16x8*)&hs[(size_t)ab * bstr + ka + aks];
  {
    int kw = ka + wkk;
    int nn = kw & 1023, cc = kw >> 10;
    const float* wp = &W[((size_t)nn * 192 + wofs + cc) * 256 + woq];
#pragma unroll
    for (int i = 0; i < 8; ++i) wv[i] = *(const float4*)(wp + i * 4);
  }
  for (int kit = 0; kit < 16; ++kit) {
    float4 f0, f1;
    f0.x = bf2f(av[0]); f0.y = bf2f(av[1]); f0.z = bf2f(av[2]); f0.w = bf2f(av[3]);
    f1.x = bf2f(av[4]); f1.y = bf2f(av[5]); f1.z = bf2f(av[6]); f1.w = bf2f(av[7]);
    *(float4*)&As[ab][aks] = f0;
    *(float4*)&As[ab][aks + 4] = f1;
#pragma unroll
    for (int i = 0; i < 8; ++i) *(float4*)&Ws[wkk][woq + i * 4] = wv[i];
    __syncthreads();
    if (kit + 1 < 16) {
      ka = kloc + (kit + 1) * 32;
      av = *(const u16x8*)&hs[(size_t)ab * bstr + ka + aks];
      int kw = ka + wkk;
      int nn = kw & 1023, cc = kw >> 10;
      const float* wp = &W[((size_t)nn * 192 + wofs + cc) * 256 + woq];
#pragma unroll
      for (int i = 0; i < 8; ++i) wv[i] = *(const float4*)(wp + i * 4);
    }
#pragma unroll
    for (int kk = 0; kk < 32; ++kk) {
      float a[4];
      a[0] = As[ty * 4 + 0][kk]; a[1] = As[ty * 4 + 1][kk];
      a[2] = As[ty * 4 + 2][kk]; a[3] = As[ty * 4 + 3][kk];
#pragma unroll
      for (int q = 0; q < 4; ++q) {
        float bb[4];
        *(float4*)bb = *(const float4*)&Ws[kk][q * 64 + tx * 4];
#pragma unroll
        for (int i = 0; i < 4; ++i)
#pragma unroll
          for (int j = 0; j < 4; ++j) acc[i][q * 4 + j] += a[i] * bb[j];
      }
    }
    __syncthreads();
  }
#pragma unroll
  for (int i = 0; i < 4; ++i)
#pragma unroll
    for (int q = 0; q < 4; ++q) {
      float4 v;
      v.x = acc[i][q * 4 + 0]; v.y = acc[i][q * 4 + 1];
      v.z = acc[i][q * 4 + 2]; v.w = acc[i][q * 4 + 3];
      *(float4*)&P[(((size_t)mat * 384 + ch) * 64 + ty * 4 + i) * 256 + q * 64 + tx * 4] = v;
    }
}

// ---------------- threefry / eps ----------------------------------------------------
__device__ __forceinline__ unsigned rotl32(unsigned v, int s) {
  return (v << s) | (v >> (32 - s));
}
__device__ void threefry(unsigned k0, unsigned k1, unsigned x0, unsigned x1,
                         unsigned& o0, unsigned& o1) {
  unsigned ks2 = k0 ^ k1 ^ 0x1BD11BDAu;
  unsigned a = x0 + k0, b = x1 + k1;
#define TF_RND(rot) { a += b; b = rotl32(b, rot); b ^= a; }
  TF_RND(13) TF_RND(15) TF_RND(26) TF_RND(6)
  a += k1; b += ks2 + 1u;
  TF_RND(17) TF_RND(29) TF_RND(16) TF_RND(24)
  a += ks2; b += k0 + 2u;
  TF_RND(13) TF_RND(15) TF_RND(26) TF_RND(6)
  a += k0; b += k1 + 3u;
  TF_RND(17) TF_RND(29) TF_RND(16) TF_RND(24)
  a += k1; b += ks2 + 4u;
  TF_RND(13) TF_RND(15) TF_RND(26) TF_RND(6)
  a += ks2; b += k0 + 5u;
#undef TF_RND
  o0 = a; o1 = b;
}

__device__ float u32_to_normal(unsigned bits) {
  unsigned fb = (bits >> 9) | 0x3F800000u;
  float f = __uint_as_float(fb) - 1.0f;
  const float lo = -0.99999994f;
  float u = f * 2.0f + lo;
  u = fmaxf(lo, u);
  float w = -log1pf(-u * u);
  float p;
  if (w < 5.0f) {
    w -= 2.5f;
    p = 2.81022636e-08f;
    p = fmaf(p, w, 3.43273939e-07f);
    p = fmaf(p, w, -3.5233877e-06f);
    p = fmaf(p, w, -4.39150654e-06f);
    p = fmaf(p, w, 0.00021858087f);
    p = fmaf(p, w, -0.00125372503f);
    p = fmaf(p, w, -0.00417768164f);
    p = fmaf(p, w, 0.246640727f);
    p = fmaf(p, w, 1.50140941f);
  } else {
    w = sqrtf(w) - 3.0f;
    p = -0.000200214257f;
    p = fmaf(p, w, 0.000100950558f);
    p = fmaf(p, w, 0.00134934322f);
    p = fmaf(p, w, -0.00367342844f);
    p = fmaf(p, w, 0.00573950773f);
    p = fmaf(p, w, -0.0076224613f);
    p = fmaf(p, w, 0.00943887047f);
    p = fmaf(p, w, 1.00167406f);
    p = fmaf(p, w, 2.83297682f);
  }
  return 1.41421354f * (p * u);
}

__global__ __launch_bounds__(256) void eps_kernel(float* __restrict__ eps) {
  int b = blockIdx.x;
  int o = threadIdx.x;
  unsigned k0, k1;
  threefry(0u, 0u, 0u, 1234u, k0, k1);
  float s = 0.f;
  for (int smp = 0; smp < 50; ++smp) {
    unsigned idx = ((unsigned)smp * 64u + (unsigned)b) * 256u + (unsigned)o;
    unsigned o0, o1, bits;
#if EPS_MODE == 0
    threefry(k0, k1, 0u, idx, o0, o1);
    bits = o0 ^ o1;
#else
    unsigned pp = idx % 409600u, half = idx / 409600u;
    threefry(k0, k1, pp, pp + 409600u, o0, o1);
    bits = half ? o1 : o0;
#endif
    s += u32_to_normal(bits);
  }
  eps[b * 256 + o] = s / 50.0f;
}

// ---------------- final reduce + heads + reparam ------------------------------------
__global__ __launch_bounds__(256) void final_kernel(const float* __restrict__ P,
                                                    const float* __restrict__ bmu,
                                                    const float* __restrict__ blv,
                                                    const float* __restrict__ eps,
                                                    float* __restrict__ out) {
  int b = blockIdx.x, o = threadIdx.x;
  float smu = 0.f, slv = 0.f;
  for (int ch = 0; ch < 384; ++ch) {
    smu += P[(((size_t)0 * 384 + ch) * 64 + b) * 256 + o];
    slv += P[(((size_t)1 * 384 + ch) * 64 + b) * 256 + o];
  }
  float mu = 1.f / (1.f + expf(-(smu + bmu[o])));
  float lv = 1.f / (1.f + expf(-(slv + blv[o])));
  float z = mu + eps[b * 256 + o] * expf(0.5f * lv);
  out[b * 256 + o] = z;
  out[16384 + b * 256 + o] = mu;
  out[32768 + b * 256 + o] = lv;
}

// ------------------------------------------------------------------------------------
extern "C" void kernel_launch(void* const* d_in, const int* in_sizes, int n_in,
                              void* d_out, int out_size, void* d_ws, size_t ws_size,
                              hipStream_t stream) {
  (void)in_sizes; (void)n_in; (void)out_size; (void)ws_size;
  const float* xs  = (const float*)d_in[0];
  const float* adj = (const float*)d_in[1];
  const float* Wz0 = (const float*)d_in[2];  const float* bz0 = (const float*)d_in[3];
  const float* Wr0 = (const float*)d_in[4];  const float* br0 = (const float*)d_in[5];
  const float* Wn0 = (const float*)d_in[6];  const float* bn0 = (const float*)d_in[7];
  const float* Wz1 = (const float*)d_in[8];  const float* bz1 = (const float*)d_in[9];
  const float* Wr1 = (const float*)d_in[10]; const float* br1 = (const float*)d_in[11];
  const float* Wn1 = (const float*)d_in[12]; const float* bn1 = (const float*)d_in[13];
  const float* Wmu = (const float*)d_in[14]; const float* bmu = (const float*)d_in[15];
  const float* Wlv = (const float*)d_in[16]; const float* blv = (const float*)d_in[17];

  float* ws = (float*)d_ws;
  // layout (units of MF f32)
  u16*  adjB  = (u16*)(ws);                  // 0.0  (0.5)
  u16*  xsB   = (u16*)(ws + MF / 2);         // 0.5  (0.5)
  float* AXv  = ws + 1 * MF;                 // 1.0  (1.0)  [t][b][n] f32
  u16*  h1T   = (u16*)(ws + 2 * MF);         // 2.0  (2.0)  [b][64][1024]
  u16*  h2T   = (u16*)(ws + 4 * MF);         // 4.0  (4.0)  [b][128][1024]
  u16*  z0T   = (u16*)(ws + 8 * MF);         // 8.0  (2.0)
  u16*  z1T   = (u16*)(ws + 10 * MF);        // 10.0 (4.0)
  u16*  rh0T  = (u16*)(ws + 14 * MF);        // 14.0 (2.0)
  u16*  rh1T  = (u16*)(ws + 16 * MF);        // 16.0 (4.0)
  u16*  AH1   = (u16*)(ws + 20 * MF);        // 20.0 (2.0)  [b][n][64]
  u16*  AH2   = (u16*)(ws + 22 * MF);        // 22.0 (4.0)  [b][n][128]
  u16*  WTb   = (u16*)(ws + 26 * MF);        // 26.0 (0.125)
  float* P    = ws + 26 * MF + MF / 4;       // 26.25 (12.6) dense partials
  float* EPS  = ws + 39 * MF;                // 39.0

  u16* WzrT0 = WTb;
  u16* WnT0  = WTb + 8192;
  u16* WzrT1 = WTb + 12288;
  u16* WnT1  = WTb + 61440;

  // zero initial state h1T,h2T (2..8 MF) and AH1,AH2 (20..26 MF)
  hipMemsetAsync(ws + 2 * MF, 0, 6 * MF * sizeof(float), stream);
  hipMemsetAsync(ws + 20 * MF, 0, 6 * MF * sizeof(float), stream);

  cast_bf16<<<1024, 256, 0, stream>>>(adj, adjB, 1 << 20);
  cast_bf16<<<1024, 256, 0, stream>>>(xs, xsB, 1 << 20);
  prep_wt<<<dim3(192, 4), 256, 0, stream>>>(Wz0, Wr0, Wn0, Wz1, Wr1, Wn1,
                                            WzrT0, WnT0, WzrT1, WnT1);

  // AX[t][b][n] = adj @ x_t for all t (cols = (t,b))
  adj_mfma<1, 0><<<dim3(8, 8), 256, 0, stream>>>(adjB, xsB, AXv);

  for (int t = 0; t < T; ++t) {
    const float* AXt = AXv + (size_t)t * 65536;
    // ---- layer 0 (C=64) ----
    gate_zr<2, 2, 64, 1, 1, 1><<<512, 256, 0, stream>>>(
        AH1, nullptr, WzrT0, bz0, br0, AXt, Wz0, Wr0, h1T, z0T, rh0T);
    adj_ngate<64, 1><<<dim3(32, 8), 256, 0, stream>>>(
        adjB, rh0T, WnT0, bn0, AXt, Wn0, nullptr, z0T, h1T);
    adj_mfma<0, 6><<<dim3(32, 8), 256, 0, stream>>>(adjB, h1T, AH1);
    // ---- layer 1 (C=128) ----
    gate_zr<1, 4, 128, 1, 3, 0><<<1024, 256, 0, stream>>>(
        AH1, AH2, WzrT1, bz1, br1, nullptr, nullptr, nullptr, h2T, z1T, rh1T);
    adj_ngate<128, 0><<<dim3(64, 8), 256, 0, stream>>>(
        adjB, rh1T, WnT1, bn1, nullptr, nullptr, AH1, z1T, h2T);
    if (t + 1 < T)
      adj_mfma<0, 7><<<dim3(64, 8), 256, 0, stream>>>(adjB, h2T, AH2);
  }

  // dense heads (reads h1T/h2T directly, k' = c*1024+n order)
  dense_gemm<<<dim3(384, 2), 256, 0, stream>>>(h1T, h2T, Wmu, Wlv, P);
  eps_kernel<<<64, 256, 0, stream>>>(EPS);
  final_kernel<<<64, 256, 0, stream>>>(P, bmu, blv, EPS, (float*)d_out);
}

// Round 4
// 3024.671 us; speedup vs baseline: 5.6537x; 1.0925x over previous
//
#include <hip/hip_runtime.h>
#include <math.h>

#define EPS_MODE 0

typedef unsigned short u16;
typedef short bf16x8 __attribute__((ext_vector_type(8)));
typedef float f32x4 __attribute__((ext_vector_type(4)));
typedef u16 u16x4 __attribute__((ext_vector_type(4)));
typedef u16 u16x8 __attribute__((ext_vector_type(8)));

static constexpr int T = 16;
static constexpr size_t MF = 1u << 20;
static constexpr int DKCH = 256;          // dense split-K chunks
static constexpr int DKCHUNK = 196608 / DKCH;  // 768

__device__ __forceinline__ u16 f2bf(float f) {
  unsigned u = __float_as_uint(f);
  unsigned r = (u + 0x7fffu + ((u >> 16) & 1u)) >> 16;
  return (u16)r;
}
__device__ __forceinline__ float bf2f(u16 h) {
  return __uint_as_float(((unsigned)h) << 16);
}
__device__ __forceinline__ void gload16(const void* g, void* l) {
  __builtin_amdgcn_global_load_lds(
      (const __attribute__((address_space(1))) void*)g,
      (__attribute__((address_space(3))) void*)l, 16, 0, 0);
}

// ---------------- casts -------------------------------------------------------------
__global__ __launch_bounds__(256) void cast_bf16(const float* __restrict__ in,
                                                 u16* __restrict__ out, int n) {
  int i = (blockIdx.x * 256 + threadIdx.x) * 4;
  if (i < n) {
    float4 v = *reinterpret_cast<const float4*>(&in[i]);
    out[i + 0] = f2bf(v.x); out[i + 1] = f2bf(v.y);
    out[i + 2] = f2bf(v.z); out[i + 3] = f2bf(v.w);
  }
}

// ---------------- W transpose+cast: WT[col][k] --------------------------------------
__global__ __launch_bounds__(256) void prep_wt(const float* __restrict__ Wz0, const float* __restrict__ Wr0,
                                               const float* __restrict__ Wn0, const float* __restrict__ Wz1,
                                               const float* __restrict__ Wr1, const float* __restrict__ Wn1,
                                               u16* __restrict__ WzrT0, u16* __restrict__ WnT0,
                                               u16* __restrict__ WzrT1, u16* __restrict__ WnT1) {
  int seg = blockIdx.y;
  int idx = blockIdx.x * 256 + threadIdx.x;
  if (seg == 0) {        // [128 out][64 k] : z|r, h-part rows 1..64
    if (idx < 128 * 64) {
      int j = idx >> 6, k = idx & 63;
      float v = (j < 64) ? Wz0[(k + 1) * 64 + j] : Wr0[(k + 1) * 64 + (j - 64)];
      WzrT0[idx] = f2bf(v);
    }
  } else if (seg == 1) {  // [64][64]
    if (idx < 64 * 64) {
      int j = idx >> 6, k = idx & 63;
      WnT0[idx] = f2bf(Wn0[(k + 1) * 64 + j]);
    }
  } else if (seg == 2) {  // [256][192]
    if (idx < 256 * 192) {
      int j = idx / 192, k = idx % 192;
      float v = (j < 128) ? Wz1[k * 128 + j] : Wr1[k * 128 + (j - 128)];
      WzrT1[idx] = f2bf(v);
    }
  } else {                // [128][192]
    if (idx < 128 * 192) {
      int j = idx / 192, k = idx % 192;
      WnT1[idx] = f2bf(Wn1[k * 128 + j]);
    }
  }
}

// ---------------- plain adjacency MFMA GEMM -----------------------------------------
// OUT[row][col] = sum_k A[row][k] * BT[col][k]   ((MFR*32-row blocks) x 128-col blocks)
// EPI 0: OUT bf16 [b][n][C]: col=(b<<LOGC)+c
// EPI 1: OUT f32 AX [t][b][n]: col=(t<<6)+b
template <int EPI, int LOGC, int MFR>
__global__ __launch_bounds__(256) void adj_mfma(const u16* __restrict__ A,
                                                const u16* __restrict__ BT,
                                                void* __restrict__ OUT) {
  constexpr int MT = MFR * 32;
  __shared__ __align__(16) char lds[(MFR + 4) * 4096];
  int tid = threadIdx.x;
  int w = tid >> 6, lane = tid & 63;
  int row0 = blockIdx.y * MT, col0 = blockIdx.x * 128;
  int wm = w >> 1, wn = w & 1;
  f32x4 acc[MFR][4] = {};
  for (int k0 = 0; k0 < 1024; k0 += 64) {
#pragma unroll
    for (int q = 0; q < MFR; ++q) {
      int row = q * 32 + w * 8 + (lane >> 3);
      gload16(A + (size_t)(row0 + row) * 1024 + k0 + (lane & 7) * 8,
              lds + q * 4096 + w * 1024);
    }
#pragma unroll
    for (int q = 0; q < 4; ++q) {
      int row = q * 32 + w * 8 + (lane >> 3);
      gload16(BT + (size_t)(col0 + row) * 1024 + k0 + (lane & 7) * 8,
              lds + MFR * 4096 + q * 4096 + w * 1024);
    }
    __syncthreads();
#pragma unroll
    for (int kk = 0; kk < 2; ++kk) {
      bf16x8 a[MFR], bb[4];
#pragma unroll
      for (int m = 0; m < MFR; ++m)
        a[m] = *(const bf16x8*)(lds + (wm * (MFR * 16) + m * 16 + (lane & 15)) * 128 + kk * 64 + (lane >> 4) * 16);
#pragma unroll
      for (int n = 0; n < 4; ++n)
        bb[n] = *(const bf16x8*)(lds + MFR * 4096 + (wn * 64 + n * 16 + (lane & 15)) * 128 + kk * 64 + (lane >> 4) * 16);
#pragma unroll
      for (int m = 0; m < MFR; ++m)
#pragma unroll
        for (int n = 0; n < 4; ++n)
          acc[m][n] = __builtin_amdgcn_mfma_f32_16x16x32_bf16(a[m], bb[n], acc[m][n], 0, 0, 0);
    }
    __syncthreads();
  }
  if (EPI == 1) {
    float* O = (float*)OUT;
#pragma unroll
    for (int m = 0; m < MFR; ++m)
#pragma unroll
      for (int n = 0; n < 4; ++n) {
        int col = col0 + wn * 64 + n * 16 + (lane & 15);
        int t = col >> 6, bbx = col & 63;
        int row = row0 + wm * (MFR * 16) + m * 16 + ((lane >> 4) << 2);
        *(float4*)&O[((size_t)t << 16) + ((size_t)bbx << 10) + row] = *(float4*)&acc[m][n];
      }
  } else {
    u16* O = (u16*)OUT;
    constexpr int C = 1 << LOGC;
#pragma unroll
    for (int m = 0; m < MFR; ++m)
#pragma unroll
      for (int n = 0; n < 4; ++n) {
        int col = col0 + wn * 64 + n * 16 + (lane & 15);
        int bbx = col >> LOGC, c = col & (C - 1);
#pragma unroll
        for (int j = 0; j < 4; ++j) {
          int row = row0 + wm * (MFR * 16) + m * 16 + ((lane >> 4) << 2) + j;
          O[(((size_t)bbx << 10) + row) * C + c] = f2bf(acc[m][n][j]);
        }
      }
  }
}

// ---------------- fused adj@(r*h) + n-gate + GRU update -----------------------------
template <int C, int RK1, int MFR>
__global__ __launch_bounds__(256) void adj_ngate(
    const u16* __restrict__ A, const u16* __restrict__ BT,
    const u16* __restrict__ WnT, const float* __restrict__ bias,
    const float* __restrict__ axv, const float* __restrict__ wx,
    const u16* __restrict__ AH1, const u16* __restrict__ zT,
    u16* __restrict__ hT) {
  constexpr int LOGC = (C == 64) ? 6 : 7;
  constexpr int KW = (C == 64) ? 64 : 192;
  constexpr int KKAN = C / 32;
  constexpr int MT = MFR * 32;
  constexpr int STG = (MFR + 4) * 4096;
  constexpr int ANBYTES = MT * 136 * 2;
  constexpr int LDSZ = STG > ANBYTES ? STG : ANBYTES;
  __shared__ __align__(16) char lds[LDSZ];
  int tid = threadIdx.x;
  int w = tid >> 6, lane = tid & 63;
  int row0 = blockIdx.y * MT, col0 = blockIdx.x * 128;
  int wm = w >> 1, wn = w & 1;
  f32x4 acc[MFR][4] = {};
  for (int k0 = 0; k0 < 1024; k0 += 64) {
#pragma unroll
    for (int q = 0; q < MFR; ++q) {
      int row = q * 32 + w * 8 + (lane >> 3);
      gload16(A + (size_t)(row0 + row) * 1024 + k0 + (lane & 7) * 8,
              lds + q * 4096 + w * 1024);
    }
#pragma unroll
    for (int q = 0; q < 4; ++q) {
      int row = q * 32 + w * 8 + (lane >> 3);
      gload16(BT + (size_t)(col0 + row) * 1024 + k0 + (lane & 7) * 8,
              lds + MFR * 4096 + q * 4096 + w * 1024);
    }
    __syncthreads();
#pragma unroll
    for (int kk = 0; kk < 2; ++kk) {
      bf16x8 a[MFR], bb[4];
#pragma unroll
      for (int m = 0; m < MFR; ++m)
        a[m] = *(const bf16x8*)(lds + (wm * (MFR * 16) + m * 16 + (lane & 15)) * 128 + kk * 64 + (lane >> 4) * 16);
#pragma unroll
      for (int n = 0; n < 4; ++n)
        bb[n] = *(const bf16x8*)(lds + MFR * 4096 + (wn * 64 + n * 16 + (lane & 15)) * 128 + kk * 64 + (lane >> 4) * 16);
#pragma unroll
      for (int m = 0; m < MFR; ++m)
#pragma unroll
        for (int n = 0; n < 4; ++n)
          acc[m][n] = __builtin_amdgcn_mfma_f32_16x16x32_bf16(a[m], bb[n], acc[m][n], 0, 0, 0);
    }
    __syncthreads();
  }
  // acc -> ANt bf16, row stride 136 u16
  u16* ANt = (u16*)lds;
#pragma unroll
  for (int m = 0; m < MFR; ++m)
#pragma unroll
    for (int n = 0; n < 4; ++n) {
      int cl = wn * 64 + n * 16 + (lane & 15);
      int rl = wm * (MFR * 16) + m * 16 + ((lane >> 4) << 2);
#pragma unroll
      for (int j = 0; j < 4; ++j)
        ANt[(rl + j) * 136 + cl] = f2bf(acc[m][n][j]);
    }
  __syncthreads();
  // gate phase
  int wrow = w >> 1, half = w & 1;
  int arow0 = wrow * (MFR * 16);
  int b0 = col0 >> LOGC;
  int out0 = (C == 64) ? 0 : half * 64;
  int kbase = (C == 64) ? half * 64 : 0;
  int b_eff = (C == 64) ? (b0 + half) : b0;
  constexpr int WOFF = (C == 64) ? 0 : 64;
  f32x4 acc2[MFR][4] = {};
#pragma unroll
  for (int kk = 0; kk < KKAN; ++kk) {
    bf16x8 a[MFR], bb[4];
    int ka = kbase + kk * 32 + (lane >> 4) * 8;
#pragma unroll
    for (int m = 0; m < MFR; ++m)
      a[m] = *(const bf16x8*)&ANt[(arow0 + m * 16 + (lane & 15)) * 136 + ka];
#pragma unroll
    for (int n = 0; n < 4; ++n)
      bb[n] = *(const bf16x8*)&WnT[(size_t)(out0 + n * 16 + (lane & 15)) * KW + WOFF + kk * 32 + (lane >> 4) * 8];
#pragma unroll
    for (int m = 0; m < MFR; ++m)
#pragma unroll
      for (int n = 0; n < 4; ++n)
        acc2[m][n] = __builtin_amdgcn_mfma_f32_16x16x32_bf16(a[m], bb[n], acc2[m][n], 0, 0, 0);
  }
  if (C == 128) {  // + AH1 (x) part, K=64
#pragma unroll
    for (int kk = 0; kk < 2; ++kk) {
      bf16x8 a[MFR], bb[4];
#pragma unroll
      for (int m = 0; m < MFR; ++m)
        a[m] = *(const bf16x8*)&AH1[(((size_t)b0 << 10) + row0 + arow0 + m * 16 + (lane & 15)) * 64 + kk * 32 + (lane >> 4) * 8];
#pragma unroll
      for (int n = 0; n < 4; ++n)
        bb[n] = *(const bf16x8*)&WnT[(size_t)(out0 + n * 16 + (lane & 15)) * 192 + kk * 32 + (lane >> 4) * 8];
#pragma unroll
      for (int m = 0; m < MFR; ++m)
#pragma unroll
        for (int n = 0; n < 4; ++n)
          acc2[m][n] = __builtin_amdgcn_mfma_f32_16x16x32_bf16(a[m], bb[n], acc2[m][n], 0, 0, 0);
    }
  }
  // epilogue: n=tanh, h=(1-z)h+z*n, in-place hT
#pragma unroll
  for (int m = 0; m < MFR; ++m) {
    float ax4[4];
    if (RK1) {
      float4 v = *(const float4*)&axv[((size_t)b_eff << 10) + row0 + arow0 + m * 16 + ((lane >> 4) << 2)];
      ax4[0] = v.x; ax4[1] = v.y; ax4[2] = v.z; ax4[3] = v.w;
    }
#pragma unroll
    for (int n = 0; n < 4; ++n) {
      int cp = out0 + n * 16 + (lane & 15);
      int grow = arow0 + m * 16 + ((lane >> 4) << 2);
      size_t idx = (((size_t)b_eff << LOGC) + cp) * 1024 + row0 + grow;
      u16x4 zv = *(const u16x4*)&zT[idx];
      u16x4 hv = *(const u16x4*)&hT[idx];
      u16x4 pk;
#pragma unroll
      for (int j = 0; j < 4; ++j) {
        float g = acc2[m][n][j] + bias[cp];
        if (RK1) g += ax4[j] * wx[cp];
        float nv = tanhf(g);
        float z = bf2f(zv[j]), ho = bf2f(hv[j]);
        pk[j] = f2bf((1.f - z) * ho + z * nv);
      }
      *(u16x4*)&hT[idx] = pk;
    }
  }
}

// ---------------- zr gate GEMM: z/r = sigmoid(.), emits zT and rhT=r*h (bf16, ^T) ---
template <int WM, int WN, int C, int NK1, int NK, int RK1>
__global__ __launch_bounds__(256) void gate_zr(
    const u16* __restrict__ A1, const u16* __restrict__ A2,
    const u16* __restrict__ WT, const float* __restrict__ bz,
    const float* __restrict__ br, const float* __restrict__ axv,
    const float* __restrict__ wxz, const float* __restrict__ wxr,
    const u16* __restrict__ hT, u16* __restrict__ zTo, u16* __restrict__ rhTo) {
  constexpr int MT = WM * 64, NT = WN * 64, K = NK * 64;
  constexpr int NB = 1024 / MT;
  __shared__ __align__(16) char lds[MT * 128 + NT * 128];
  int tid = threadIdx.x;
  int w = tid >> 6, lane = tid & 63;
  int by = blockIdx.x;
  int b = by / NB, n0 = (by % NB) * MT;
  size_t row0 = ((size_t)b << 10) + n0;
  int wm = w / WN, wn = w % WN;
  f32x4 acc[4][4] = {};
  for (int s = 0; s < NK; ++s) {
    const u16* As; int astr, koff;
    if (s < NK1) { As = A1; astr = 64; koff = s * 64; }
    else         { As = A2; astr = 128; koff = (s - NK1) * 64; }
#pragma unroll
    for (int q = 0; q < MT / 32; ++q) {
      int row = q * 32 + w * 8 + (lane >> 3);
      gload16(As + (row0 + row) * astr + koff + (lane & 7) * 8,
              lds + q * 4096 + w * 1024);
    }
#pragma unroll
    for (int q = 0; q < NT / 32; ++q) {
      int row = q * 32 + w * 8 + (lane >> 3);
      gload16(WT + (size_t)row * K + s * 64 + (lane & 7) * 8,
              lds + MT * 128 + q * 4096 + w * 1024);
    }
    __syncthreads();
#pragma unroll
    for (int kk = 0; kk < 2; ++kk) {
      bf16x8 a[4], bb[4];
#pragma unroll
      for (int m = 0; m < 4; ++m)
        a[m] = *(const bf16x8*)(lds + (wm * 64 + m * 16 + (lane & 15)) * 128 + kk * 64 + (lane >> 4) * 16);
#pragma unroll
      for (int n = 0; n < 4; ++n)
        bb[n] = *(const bf16x8*)(lds + MT * 128 + (wn * 64 + n * 16 + (lane & 15)) * 128 + kk * 64 + (lane >> 4) * 16);
#pragma unroll
      for (int m = 0; m < 4; ++m)
#pragma unroll
        for (int n = 0; n < 4; ++n)
          acc[m][n] = __builtin_amdgcn_mfma_f32_16x16x32_bf16(a[m], bb[n], acc[m][n], 0, 0, 0);
    }
    __syncthreads();
  }
#pragma unroll
  for (int m = 0; m < 4; ++m) {
    float ax4[4];
    if (RK1) {
      float4 v = *(const float4*)&axv[row0 + wm * 64 + m * 16 + ((lane >> 4) << 2)];
      ax4[0] = v.x; ax4[1] = v.y; ax4[2] = v.z; ax4[3] = v.w;
    }
#pragma unroll
    for (int n = 0; n < 4; ++n) {
      int cp = wn * 64 + n * 16 + (lane & 15);
      bool iz = cp < C;
      int c = iz ? cp : cp - C;
      int rl = wm * 64 + m * 16 + ((lane >> 4) << 2);
      size_t idx = (((size_t)b * C + c) << 10) + n0 + rl;
      u16x4 hv;
      if (!iz) hv = *(const u16x4*)&hT[idx];
      u16x4 pk;
#pragma unroll
      for (int j = 0; j < 4; ++j) {
        float g = acc[m][n][j] + (iz ? bz : br)[c];
        if (RK1) g += ax4[j] * (iz ? wxz : wxr)[c];
        float sg = 1.f / (1.f + expf(-g));
        pk[j] = iz ? f2bf(sg) : f2bf(sg * bf2f(hv[j]));
      }
      *(u16x4*)&(iz ? zTo : rhTo)[idx] = pk;
    }
  }
}

// ---------------- transpose final states: X[b][n*192+c] bf16 ------------------------
__global__ __launch_bounds__(256) void transpose_x(const u16* __restrict__ h1T,
                                                   const u16* __restrict__ h2T,
                                                   u16* __restrict__ X) {
  int b = blockIdx.x;       // 64
  int n0 = blockIdx.y * 128;  // 8
  __shared__ u16 tile[192][136];
  int tid = threadIdx.x;
#pragma unroll
  for (int i = 0; i < 12; ++i) {
    int id = tid + i * 256;
    int c = id >> 4, g = id & 15;
    u16x8 v;
    if (c < 64) v = *(const u16x8*)&h1T[(((size_t)b << 6) + c) * 1024 + n0 + g * 8];
    else        v = *(const u16x8*)&h2T[(((size_t)b << 7) + (c - 64)) * 1024 + n0 + g * 8];
    *(u16x8*)&tile[c][g * 8] = v;
  }
  __syncthreads();
#pragma unroll
  for (int i = 0; i < 12; ++i) {
    int id = tid + i * 256;
    int n = id / 24, g = id % 24;
    u16x8 v;
#pragma unroll
    for (int j = 0; j < 8; ++j) v[j] = tile[g * 8 + j][n];
    *(u16x8*)&X[(size_t)b * 196608 + (size_t)(n0 + n) * 192 + g * 8] = v;
  }
}

// ---------------- dense head: streaming split-K, W in natural order -----------------
// P[mat][ch][64 b][256 o] partials; block tile M=64 x N=64 x K=768
__global__ __launch_bounds__(256) void dense_split(const u16* __restrict__ X,
                                                   const float* __restrict__ Wmu,
                                                   const float* __restrict__ Wlv,
                                                   float* __restrict__ P) {
  int ot = blockIdx.x, ch = blockIdx.y, mat = blockIdx.z;
  const float* W = mat ? Wlv : Wmu;
  int o0 = ot * 64;
  __shared__ float As[16][68];
  __shared__ float Ws[16][68];
  int tid = threadIdx.x;
  int tx = tid & 15, ty = tid >> 4;
  int ab = tid >> 2, akq = (tid & 3) * 4;    // X: thread covers b=ab, k-sub akq..+3
  int wkk = tid >> 4, wo4 = (tid & 15) * 4;  // W: row wkk, 4 outputs
  int kb = ch * DKCHUNK;
  float acc[4][4] = {};
  u16x4 xa = *(const u16x4*)&X[(size_t)ab * 196608 + kb + akq];
  float4 wv = *(const float4*)&W[(size_t)(kb + wkk) * 256 + o0 + wo4];
  for (int s = 0; s < DKCHUNK / 16; ++s) {
#pragma unroll
    for (int j = 0; j < 4; ++j) As[akq + j][ab] = bf2f(xa[j]);
    *(float4*)&Ws[wkk][wo4] = wv;
    __syncthreads();
    if (s + 1 < DKCHUNK / 16) {
      int k0 = kb + (s + 1) * 16;
      xa = *(const u16x4*)&X[(size_t)ab * 196608 + k0 + akq];
      wv = *(const float4*)&W[(size_t)(k0 + wkk) * 256 + o0 + wo4];
    }
#pragma unroll
    for (int kk = 0; kk < 16; ++kk) {
      float a[4], bq[4];
      *(float4*)a = *(const float4*)&As[kk][ty * 4];
      *(float4*)bq = *(const float4*)&Ws[kk][tx * 4];
#pragma unroll
      for (int i = 0; i < 4; ++i)
#pragma unroll
        for (int j = 0; j < 4; ++j) acc[i][j] += a[i] * bq[j];
    }
    __syncthreads();
  }
#pragma unroll
  for (int i = 0; i < 4; ++i) {
    float4 v; v.x = acc[i][0]; v.y = acc[i][1]; v.z = acc[i][2]; v.w = acc[i][3];
    *(float4*)&P[(((size_t)mat * DKCH + ch) * 64 + ty * 4 + i) * 256 + o0 + tx * 4] = v;
  }
}

// ---------------- threefry / eps ----------------------------------------------------
__device__ __forceinline__ unsigned rotl32(unsigned v, int s) {
  return (v << s) | (v >> (32 - s));
}
__device__ void threefry(unsigned k0, unsigned k1, unsigned x0, unsigned x1,
                         unsigned& o0, unsigned& o1) {
  unsigned ks2 = k0 ^ k1 ^ 0x1BD11BDAu;
  unsigned a = x0 + k0, b = x1 + k1;
#define TF_RND(rot) { a += b; b = rotl32(b, rot); b ^= a; }
  TF_RND(13) TF_RND(15) TF_RND(26) TF_RND(6)
  a += k1; b += ks2 + 1u;
  TF_RND(17) TF_RND(29) TF_RND(16) TF_RND(24)
  a += ks2; b += k0 + 2u;
  TF_RND(13) TF_RND(15) TF_RND(26) TF_RND(6)
  a += k0; b += k1 + 3u;
  TF_RND(17) TF_RND(29) TF_RND(16) TF_RND(24)
  a += k1; b += ks2 + 4u;
  TF_RND(13) TF_RND(15) TF_RND(26) TF_RND(6)
  a += ks2; b += k0 + 5u;
#undef TF_RND
  o0 = a; o1 = b;
}

__device__ float u32_to_normal(unsigned bits) {
  unsigned fb = (bits >> 9) | 0x3F800000u;
  float f = __uint_as_float(fb) - 1.0f;
  const float lo = -0.99999994f;
  float u = f * 2.0f + lo;
  u = fmaxf(lo, u);
  float w = -log1pf(-u * u);
  float p;
  if (w < 5.0f) {
    w -= 2.5f;
    p = 2.81022636e-08f;
    p = fmaf(p, w, 3.43273939e-07f);
    p = fmaf(p, w, -3.5233877e-06f);
    p = fmaf(p, w, -4.39150654e-06f);
    p = fmaf(p, w, 0.00021858087f);
    p = fmaf(p, w, -0.00125372503f);
    p = fmaf(p, w, -0.00417768164f);
    p = fmaf(p, w, 0.246640727f);
    p = fmaf(p, w, 1.50140941f);
  } else {
    w = sqrtf(w) - 3.0f;
    p = -0.000200214257f;
    p = fmaf(p, w, 0.000100950558f);
    p = fmaf(p, w, 0.00134934322f);
    p = fmaf(p, w, -0.00367342844f);
    p = fmaf(p, w, 0.00573950773f);
    p = fmaf(p, w, -0.0076224613f);
    p = fmaf(p, w, 0.00943887047f);
    p = fmaf(p, w, 1.00167406f);
    p = fmaf(p, w, 2.83297682f);
  }
  return 1.41421354f * (p * u);
}

__global__ __launch_bounds__(256) void eps_kernel(float* __restrict__ eps) {
  int b = blockIdx.x;
  int o = threadIdx.x;
  unsigned k0, k1;
  threefry(0u, 0u, 0u, 1234u, k0, k1);
  float s = 0.f;
  for (int smp = 0; smp < 50; ++smp) {
    unsigned idx = ((unsigned)smp * 64u + (unsigned)b) * 256u + (unsigned)o;
    unsigned o0, o1, bits;
#if EPS_MODE == 0
    threefry(k0, k1, 0u, idx, o0, o1);
    bits = o0 ^ o1;
#else
    unsigned pp = idx % 409600u, half = idx / 409600u;
    threefry(k0, k1, pp, pp + 409600u, o0, o1);
    bits = half ? o1 : o0;
#endif
    s += u32_to_normal(bits);
  }
  eps[b * 256 + o] = s / 50.0f;
}

// ---------------- final reduce + heads + reparam ------------------------------------
__global__ __launch_bounds__(256) void final_kernel(const float* __restrict__ P,
                                                    const float* __restrict__ bmu,
                                                    const float* __restrict__ blv,
                                                    const float* __restrict__ eps,
                                                    float* __restrict__ out) {
  int b = blockIdx.x, o = threadIdx.x;
  float smu = 0.f, slv = 0.f;
  for (int ch = 0; ch < DKCH; ++ch) {
    smu += P[(((size_t)0 * DKCH + ch) * 64 + b) * 256 + o];
    slv += P[(((size_t)1 * DKCH + ch) * 64 + b) * 256 + o];
  }
  float mu = 1.f / (1.f + expf(-(smu + bmu[o])));
  float lv = 1.f / (1.f + expf(-(slv + blv[o])));
  float z = mu + eps[b * 256 + o] * expf(0.5f * lv);
  out[b * 256 + o] = z;
  out[16384 + b * 256 + o] = mu;
  out[32768 + b * 256 + o] = lv;
}

// ------------------------------------------------------------------------------------
extern "C" void kernel_launch(void* const* d_in, const int* in_sizes, int n_in,
                              void* d_out, int out_size, void* d_ws, size_t ws_size,
                              hipStream_t stream) {
  (void)in_sizes; (void)n_in; (void)out_size; (void)ws_size;
  const float* xs  = (const float*)d_in[0];
  const float* adj = (const float*)d_in[1];
  const float* Wz0 = (const float*)d_in[2];  const float* bz0 = (const float*)d_in[3];
  const float* Wr0 = (const float*)d_in[4];  const float* br0 = (const float*)d_in[5];
  const float* Wn0 = (const float*)d_in[6];  const float* bn0 = (const float*)d_in[7];
  const float* Wz1 = (const float*)d_in[8];  const float* bz1 = (const float*)d_in[9];
  const float* Wr1 = (const float*)d_in[10]; const float* br1 = (const float*)d_in[11];
  const float* Wn1 = (const float*)d_in[12]; const float* bn1 = (const float*)d_in[13];
  const float* Wmu = (const float*)d_in[14]; const float* bmu = (const float*)d_in[15];
  const float* Wlv = (const float*)d_in[16]; const float* blv = (const float*)d_in[17];

  float* ws = (float*)d_ws;
  // layout (units of MF f32)
  u16*  adjB  = (u16*)(ws);                  // 0.0  (0.5)
  u16*  xsB   = (u16*)(ws + MF / 2);         // 0.5  (0.5)
  float* AXv  = ws + 1 * MF;                 // 1.0  (1.0)  [t][b][n] f32
  u16*  h1T   = (u16*)(ws + 2 * MF);         // 2.0  (2.0)  [b][64][1024]
  u16*  h2T   = (u16*)(ws + 4 * MF);         // 4.0  (4.0)  [b][128][1024]
  u16*  z0T   = (u16*)(ws + 8 * MF);         // 8.0  (2.0)
  u16*  z1T   = (u16*)(ws + 10 * MF);        // 10.0 (4.0)
  u16*  rh0T  = (u16*)(ws + 14 * MF);        // 14.0 (2.0)
  u16*  rh1T  = (u16*)(ws + 16 * MF);        // 16.0 (4.0)
  u16*  AH1   = (u16*)(ws + 20 * MF);        // 20.0 (2.0)  [b][n][64]
  u16*  AH2   = (u16*)(ws + 22 * MF);        // 22.0 (4.0)  [b][n][128]
  u16*  WTb   = (u16*)(ws + 26 * MF);        // 26.0 (0.125)
  // post-loop aliases (dead loop buffers):
  u16*  X     = (u16*)(ws + 8 * MF);         // 8.0  (6.0)  [b][196608] bf16
  float* P    = ws + 16 * MF;                // 16.0 (8.0)  dense partials
  float* EPS  = ws + 24 * MF;                // 24.0

  u16* WzrT0 = WTb;
  u16* WnT0  = WTb + 8192;
  u16* WzrT1 = WTb + 12288;
  u16* WnT1  = WTb + 61440;

  // zero initial state h1T,h2T (2..8 MF) and AH1,AH2 (20..26 MF)
  hipMemsetAsync(ws + 2 * MF, 0, 6 * MF * sizeof(float), stream);
  hipMemsetAsync(ws + 20 * MF, 0, 6 * MF * sizeof(float), stream);

  cast_bf16<<<1024, 256, 0, stream>>>(adj, adjB, 1 << 20);
  cast_bf16<<<1024, 256, 0, stream>>>(xs, xsB, 1 << 20);
  prep_wt<<<dim3(192, 4), 256, 0, stream>>>(Wz0, Wr0, Wn0, Wz1, Wr1, Wn1,
                                            WzrT0, WnT0, WzrT1, WnT1);

  // AX[t][b][n] = adj @ x_t for all t (cols = (t,b))
  adj_mfma<1, 0, 4><<<dim3(8, 8), 256, 0, stream>>>(adjB, xsB, AXv);

  for (int t = 0; t < T; ++t) {
    const float* AXt = AXv + (size_t)t * 65536;
    // ---- layer 0 (C=64) ----
    gate_zr<2, 2, 64, 1, 1, 1><<<512, 256, 0, stream>>>(
        AH1, nullptr, WzrT0, bz0, br0, AXt, Wz0, Wr0, h1T, z0T, rh0T);
    adj_ngate<64, 1, 2><<<dim3(32, 16), 256, 0, stream>>>(
        adjB, rh0T, WnT0, bn0, AXt, Wn0, nullptr, z0T, h1T);
    adj_mfma<0, 6, 2><<<dim3(32, 16), 256, 0, stream>>>(adjB, h1T, AH1);
    // ---- layer 1 (C=128) ----
    gate_zr<1, 4, 128, 1, 3, 0><<<1024, 256, 0, stream>>>(
        AH1, AH2, WzrT1, bz1, br1, nullptr, nullptr, nullptr, h2T, z1T, rh1T);
    adj_ngate<128, 0, 4><<<dim3(64, 8), 256, 0, stream>>>(
        adjB, rh1T, WnT1, bn1, nullptr, nullptr, AH1, z1T, h2T);
    if (t + 1 < T)
      adj_mfma<0, 7, 4><<<dim3(64, 8), 256, 0, stream>>>(adjB, h2T, AH2);
  }

  // dense heads: transpose states to natural-k order, then stream W
  transpose_x<<<dim3(64, 8), 256, 0, stream>>>(h1T, h2T, X);
  dense_split<<<dim3(4, DKCH, 2), 256, 0, stream>>>(X, Wmu, Wlv, P);
  eps_kernel<<<64, 256, 0, stream>>>(EPS);
  final_kernel<<<64, 256, 0, stream>>>(P, bmu, blv, EPS, (float*)d_out);
}